// Round 1
// baseline (921.745 us; speedup 1.0000x reference)
//
#include <hip/hip_runtime.h>

typedef unsigned int u32;

// ---- JAX threefry2x32 (20 rounds), bit-exact -------------------------------
__host__ __device__ inline void tf2x32(u32 k0, u32 k1, u32 x0, u32 x1,
                                       u32* y0, u32* y1) {
    u32 ks2 = k0 ^ k1 ^ 0x1BD11BDAu;
#define TFR(r) { x0 += x1; x1 = (x1 << (r)) | (x1 >> (32 - (r))); x1 ^= x0; }
    x0 += k0; x1 += k1;
    TFR(13) TFR(15) TFR(26) TFR(6)
    x0 += k1;  x1 += ks2 + 1u;
    TFR(17) TFR(29) TFR(16) TFR(24)
    x0 += ks2; x1 += k0 + 2u;
    TFR(13) TFR(15) TFR(26) TFR(6)
    x0 += k0;  x1 += k1 + 3u;
    TFR(17) TFR(29) TFR(16) TFR(24)
    x0 += k1;  x1 += ks2 + 4u;
    TFR(13) TFR(15) TFR(26) TFR(6)
    x0 += ks2; x1 += k0 + 5u;
#undef TFR
    *y0 = x0; *y1 = x1;
}

// Partitionable random_bits(key, 32, shape): bits(i) = y0^y1 of ctr=(0, i).
// uniform = bitcast((bits>>9)|0x3f800000)-1 ; keep iff u < 0.7f ; scale 1/0.7.
__device__ inline float drop_scale(float v, u32 k0, u32 k1, u32 idx) {
    u32 y0, y1;
    tf2x32(k0, k1, 0u, idx, &y0, &y1);
    u32 bits = y0 ^ y1;
    float u = __uint_as_float((bits >> 9) | 0x3f800000u) - 1.0f;
    return (u < 0.7f) ? (v / 0.7f) : 0.0f;
}

// ---- int32/int64 index handling --------------------------------------------
__global__ void k_detect(const u32* p, int* flag) {
    if (blockIdx.x == 0 && threadIdx.x == 0) {
        int all0 = 1;
        for (int i = 0; i < 64; ++i)
            if (p[2 * i + 1] != 0u) { all0 = 0; break; }
        *flag = all0;   // 1 => data is int64 (odd words are high halves == 0)
    }
}

__device__ inline int idx_at(const void* p, long i, int is64) {
    return is64 ? (int)((const long long*)p)[i] : ((const int*)p)[i];
}

// ---- kernels ---------------------------------------------------------------
__global__ void k_deg(const void* ei, int E, const int* flag, float* deg) {
    int e = blockIdx.x * blockDim.x + threadIdx.x;
    if (e >= E) return;
    int d = idx_at(ei, (long)E + e, *flag);
    atomicAdd(&deg[d], 1.0f);
}

__global__ void k_dinv(float* deg, int N) {
    int n = blockIdx.x * blockDim.x + threadIdx.x;
    if (n < N) deg[n] = 1.0f / sqrtf(deg[n] + 1.0f);
}

// out[N,64] = in[N,64] @ W[64,64]; 4 rows per 256-thread block, W in LDS.
__global__ void k_gemm64(const float* __restrict__ in, const float* __restrict__ W,
                         float* __restrict__ out, int N) {
    __shared__ float Ws[64 * 64];
    __shared__ float xs[4 * 64];
    int tid = threadIdx.x;
#pragma unroll
    for (int i = 0; i < 16; ++i) Ws[tid + i * 256] = W[tid + i * 256];
    int row0 = blockIdx.x * 4;
    long gi = (long)row0 * 64 + tid;
    xs[tid] = (gi < (long)N * 64) ? in[gi] : 0.0f;
    __syncthreads();
    int r = tid >> 6, c = tid & 63;
    int row = row0 + r;
    if (row >= N) return;
    float acc = 0.0f;
#pragma unroll
    for (int k = 0; k < 64; ++k) acc += xs[r * 64 + k] * Ws[k * 64 + c];
    out[(long)row * 64 + c] = acc;
}

// one wave per edge, lane = feature: G[dst,f] += H[src,f]*dinv[src]*dinv[dst]
__global__ void k_scatter(const void* ei, int E, const int* flag,
                          const float* __restrict__ H,
                          const float* __restrict__ dinv,
                          float* __restrict__ G) {
    long t = (long)blockIdx.x * blockDim.x + threadIdx.x;
    int e = (int)(t >> 6);
    int f = (int)(t & 63);
    if (e >= E) return;
    int is64 = *flag;
    int s = idx_at(ei, e, is64);
    int d = idx_at(ei, (long)E + e, is64);
    float nrm = dinv[s] * dinv[d];
    atomicAdd(&G[(long)d * 64 + f], H[(long)s * 64 + f] * nrm);
}

// G[i] = G[i] + H[i]*dinv[n]^2 + b[f] ; optional relu+dropout (in place)
__global__ void k_finalize(float* __restrict__ G, const float* __restrict__ H,
                           const float* __restrict__ dinv, const float* __restrict__ b,
                           int NF, int dodrop, u32 k0, u32 k1) {
    int i = blockIdx.x * blockDim.x + threadIdx.x;
    if (i >= NF) return;
    int n = i >> 6, f = i & 63;
    float di = dinv[n];
    float v = G[i] + H[i] * di * di + b[f];
    if (dodrop) {
        v = fmaxf(v, 0.0f);
        v = drop_scale(v, k0, k1, (u32)i);
    }
    G[i] = v;
}

__global__ void k_poolsum(const float* __restrict__ A, const void* batch,
                          const int* flag, int N,
                          float* __restrict__ sums, float* __restrict__ cnt) {
    long t = (long)blockIdx.x * blockDim.x + threadIdx.x;
    int n = (int)(t >> 6), f = (int)(t & 63);
    if (n >= N) return;
    int g = idx_at(batch, n, *flag);
    atomicAdd(&sums[g * 64 + f], A[(long)n * 64 + f]);
    if (f == 0) atomicAdd(&cnt[g], 1.0f);
}

__global__ void k_poolfin(const float* __restrict__ sums, const float* __restrict__ cnt,
                          float* __restrict__ pooled, u32 k0, u32 k1, int GF) {
    int i = blockIdx.x * blockDim.x + threadIdx.x;
    if (i >= GF) return;
    int g = i >> 6;
    float c = fmaxf(cnt[g], 1.0f);
    pooled[i] = drop_scale(sums[i] / c, k0, k1, (u32)i);
}

__global__ void k_outgemm(const float* __restrict__ P, const float* __restrict__ Wl,
                          const float* __restrict__ bl, float* __restrict__ out,
                          int NG, int K, int O) {
    int i = blockIdx.x * blockDim.x + threadIdx.x;
    if (i >= NG * O) return;
    int g = i / O, o = i - g * O;
    float acc = bl[o];
    for (int k = 0; k < K; ++k) acc += P[g * K + k] * Wl[k * O + o];
    out[i] = acc;
}

// ---- launch ----------------------------------------------------------------
extern "C" void kernel_launch(void* const* d_in, const int* in_sizes, int n_in,
                              void* d_out, int out_size, void* d_ws, size_t ws_size,
                              hipStream_t stream) {
    const float* x  = (const float*)d_in[0];
    const void*  ei = d_in[1];
    const void*  bt = d_in[2];
    const float* W[3] = {(const float*)d_in[3], (const float*)d_in[5], (const float*)d_in[7]};
    const float* b[3] = {(const float*)d_in[4], (const float*)d_in[6], (const float*)d_in[8]};
    const float* Wl = (const float*)d_in[9];
    const float* bl = (const float*)d_in[10];
    float* out = (float*)d_out;

    const int F = 64;
    int N  = in_sizes[0] / F;      // 50000
    int E  = in_sizes[1] / 2;      // 800000
    int NG = 256;
    int O  = in_sizes[9] / F;      // 10
    long NF = (long)N * F;         // 3.2M

    float* ws     = (float*)d_ws;
    float* dinv   = ws;                              // N (rounded up)
    float* H      = dinv + ((N + 63) / 64) * 64;     // NF
    float* G      = H + NF;                          // NF
    float* sums   = G + NF;                          // NG*F
    float* cnt    = sums + NG * F;                   // NG
    float* pooled = cnt + NG;                        // NG*F
    int*   flag   = (int*)(pooled + NG * F);

    // Dropout keys: partitionable split => dk[i] = threefry(key, (0, i))
    u32 dk[3][2];
    for (u32 i = 0; i < 3; ++i) tf2x32(0u, 12345u, 0u, i, &dk[i][0], &dk[i][1]);

    k_detect<<<1, 64, 0, stream>>>((const u32*)ei, flag);
    hipMemsetAsync(dinv, 0, (size_t)N * 4, stream);
    k_deg<<<(E + 255) / 256, 256, 0, stream>>>(ei, E, flag, dinv);
    k_dinv<<<(N + 255) / 256, 256, 0, stream>>>(dinv, N);

    int nfBlocks = (int)((NF + 255) / 256);
    for (int l = 0; l < 3; ++l) {
        const float* inp = (l == 0) ? x : G;
        k_gemm64<<<(N + 3) / 4, 256, 0, stream>>>(inp, W[l], H, N);
        hipMemsetAsync(G, 0, (size_t)NF * 4, stream);
        long st = (long)E * 64;
        k_scatter<<<(int)((st + 255) / 256), 256, 0, stream>>>(ei, E, flag, H, dinv, G);
        k_finalize<<<nfBlocks, 256, 0, stream>>>(G, H, dinv, b[l], (int)NF,
                                                 (l < 2) ? 1 : 0, dk[l][0], dk[l][1]);
    }

    hipMemsetAsync(sums, 0, (size_t)(NG * F + NG) * 4, stream);
    k_poolsum<<<nfBlocks, 256, 0, stream>>>(G, bt, flag, N, sums, cnt);
    k_poolfin<<<(NG * F + 255) / 256, 256, 0, stream>>>(sums, cnt, pooled,
                                                        dk[2][0], dk[2][1], NG * F);
    k_outgemm<<<(NG * O + 255) / 256, 256, 0, stream>>>(pooled, Wl, bl, out, NG, F, O);
}

// Round 2
// 368.570 us; speedup vs baseline: 2.5009x; 2.5009x over previous
//
#include <hip/hip_runtime.h>

typedef unsigned int u32;

// ---- JAX threefry2x32 (20 rounds), bit-exact -------------------------------
__host__ __device__ inline void tf2x32(u32 k0, u32 k1, u32 x0, u32 x1,
                                       u32* y0, u32* y1) {
    u32 ks2 = k0 ^ k1 ^ 0x1BD11BDAu;
#define TFR(r) { x0 += x1; x1 = (x1 << (r)) | (x1 >> (32 - (r))); x1 ^= x0; }
    x0 += k0; x1 += k1;
    TFR(13) TFR(15) TFR(26) TFR(6)
    x0 += k1;  x1 += ks2 + 1u;
    TFR(17) TFR(29) TFR(16) TFR(24)
    x0 += ks2; x1 += k0 + 2u;
    TFR(13) TFR(15) TFR(26) TFR(6)
    x0 += k0;  x1 += k1 + 3u;
    TFR(17) TFR(29) TFR(16) TFR(24)
    x0 += k1;  x1 += ks2 + 4u;
    TFR(13) TFR(15) TFR(26) TFR(6)
    x0 += ks2; x1 += k0 + 5u;
#undef TFR
    *y0 = x0; *y1 = x1;
}

__device__ inline float drop_scale(float v, u32 k0, u32 k1, u32 idx) {
    u32 y0, y1;
    tf2x32(k0, k1, 0u, idx, &y0, &y1);
    u32 bits = y0 ^ y1;
    float u = __uint_as_float((bits >> 9) | 0x3f800000u) - 1.0f;
    return (u < 0.7f) ? (v / 0.7f) : 0.0f;
}

// ---- int32/int64 index handling --------------------------------------------
__global__ void k_detect(const u32* p, int* flag) {
    if (blockIdx.x == 0 && threadIdx.x == 0) {
        int all0 = 1;
        for (int i = 0; i < 64; ++i)
            if (p[2 * i + 1] != 0u) { all0 = 0; break; }
        *flag = all0;   // 1 => int64 layout
    }
}

__device__ inline int idx_at(const void* p, long i, int is64) {
    return is64 ? (int)((const long long*)p)[i] : ((const int*)p)[i];
}

// ---- CSR build -------------------------------------------------------------
__global__ void k_deg(const void* ei, int E, const int* flag, int* degi) {
    int e = blockIdx.x * blockDim.x + threadIdx.x;
    if (e >= E) return;
    atomicAdd(&degi[idx_at(ei, (long)E + e, *flag)], 1);
}

__global__ void k_dinv(const int* degi, float* dinv, int N) {
    int n = blockIdx.x * blockDim.x + threadIdx.x;
    if (n < N) dinv[n] = rsqrtf((float)degi[n] + 1.0f);
}

// exclusive scan of degi -> offs, block partials -> part
__global__ void k_scan_part(const int* degi, int* offs, int* part, int N) {
    __shared__ int s[256];
    int tid = threadIdx.x;
    int i = blockIdx.x * 256 + tid;
    int v = (i < N) ? degi[i] : 0;
    s[tid] = v; __syncthreads();
    for (int d = 1; d < 256; d <<= 1) {
        int t = (tid >= d) ? s[tid - d] : 0;
        __syncthreads();
        s[tid] += t;
        __syncthreads();
    }
    if (i < N) offs[i] = s[tid] - v;
    if (tid == 255) part[blockIdx.x] = s[255];
}

__global__ void k_scan_mid(int* part, int* offs, int P, int N, int E) {
    __shared__ int s[256];
    int tid = threadIdx.x;
    int v = (tid < P) ? part[tid] : 0;
    s[tid] = v; __syncthreads();
    for (int d = 1; d < 256; d <<= 1) {
        int t = (tid >= d) ? s[tid - d] : 0;
        __syncthreads();
        s[tid] += t;
        __syncthreads();
    }
    if (tid < P) part[tid] = s[tid] - v;  // exclusive
    if (tid == 0) offs[N] = E;
}

__global__ void k_scan_add(int* offs, const int* part, int* cursor, int N) {
    int i = blockIdx.x * 256 + threadIdx.x;
    if (i >= N) return;
    int v = offs[i] + part[blockIdx.x];
    offs[i] = v;
    cursor[i] = v;
}

// fill buckets: elist[pos] = {src, dinv[src]}
__global__ void k_bucket(const void* ei, int E, const int* flag,
                         const float* __restrict__ dinv,
                         int* __restrict__ cursor, int2* __restrict__ elist) {
    int e = blockIdx.x * blockDim.x + threadIdx.x;
    if (e >= E) return;
    int is64 = *flag;
    int s = idx_at(ei, e, is64);
    int d = idx_at(ei, (long)E + e, is64);
    int pos = atomicAdd(&cursor[d], 1);
    int2 p; p.x = s; p.y = __float_as_int(dinv[s]);
    elist[pos] = p;
}

// ---- dense 64x64 GEMM: out = in @ W ---------------------------------------
__global__ void k_gemm64(const float* __restrict__ in, const float* __restrict__ W,
                         float* __restrict__ out, int N) {
    __shared__ float Ws[64 * 64];
    __shared__ float xs[4 * 64];
    int tid = threadIdx.x;
#pragma unroll
    for (int i = 0; i < 16; ++i) Ws[tid + i * 256] = W[tid + i * 256];
    int row0 = blockIdx.x * 4;
    long gi = (long)row0 * 64 + tid;
    xs[tid] = (gi < (long)N * 64) ? in[gi] : 0.0f;
    __syncthreads();
    int r = tid >> 6, c = tid & 63;
    int row = row0 + r;
    if (row >= N) return;
    float acc = 0.0f;
#pragma unroll
    for (int k = 0; k < 64; ++k) acc += xs[r * 64 + k] * Ws[k * 64 + c];
    out[(long)row * 64 + c] = acc;
}

// ---- per-node aggregate: one wave per dst node, fused epilogue -------------
__global__ __launch_bounds__(256) void k_agg(
    const int2* __restrict__ elist, const int* __restrict__ offs,
    const float* __restrict__ dinv, const float* __restrict__ H,
    const float* __restrict__ b, float* __restrict__ G,
    int N, int dodrop, u32 k0, u32 k1) {
    int node = (int)(((long)blockIdx.x * blockDim.x + threadIdx.x) >> 6);
    int f = threadIdx.x & 63;
    if (node >= N) return;
    int beg = offs[node], end = offs[node + 1];
    float acc = 0.0f;
    int j = beg;
    for (; j + 1 < end; j += 2) {
        int2 p0 = elist[j], p1 = elist[j + 1];
        float h0 = H[(long)p0.x * 64 + f];
        float h1 = H[(long)p1.x * 64 + f];
        acc += __int_as_float(p0.y) * h0 + __int_as_float(p1.y) * h1;
    }
    if (j < end) {
        int2 p = elist[j];
        acc += __int_as_float(p.y) * H[(long)p.x * 64 + f];
    }
    float di = dinv[node];
    float v = di * acc + H[(long)node * 64 + f] * di * di + b[f];
    if (dodrop) {
        v = fmaxf(v, 0.0f);
        v = drop_scale(v, k0, k1, (u32)(node * 64 + f));
    }
    G[(long)node * 64 + f] = v;
}

// ---- pooling: one wave per 8 consecutive nodes, run-length atomics ---------
__global__ void k_poolsum(const float* __restrict__ G, const void* batch,
                          const int* flag, int N,
                          float* __restrict__ sums, float* __restrict__ cnt) {
    int wave = (int)(((long)blockIdx.x * blockDim.x + threadIdx.x) >> 6);
    int f = threadIdx.x & 63;
    int n0 = wave * 8;
    if (n0 >= N) return;
    int nend = n0 + 8 < N ? n0 + 8 : N;
    int is64 = *flag;
    float acc = 0.0f; float cacc = 0.0f; int curg = -1;
    for (int n = n0; n < nend; ++n) {
        int g = idx_at(batch, n, is64);
        if (g != curg) {
            if (curg >= 0) {
                atomicAdd(&sums[curg * 64 + f], acc);
                if (f == 0) atomicAdd(&cnt[curg], cacc);
            }
            curg = g; acc = 0.0f; cacc = 0.0f;
        }
        acc += G[(long)n * 64 + f];
        cacc += 1.0f;
    }
    if (curg >= 0) {
        atomicAdd(&sums[curg * 64 + f], acc);
        if (f == 0) atomicAdd(&cnt[curg], cacc);
    }
}

__global__ void k_poolfin(const float* __restrict__ sums, const float* __restrict__ cnt,
                          float* __restrict__ pooled, u32 k0, u32 k1, int GF) {
    int i = blockIdx.x * blockDim.x + threadIdx.x;
    if (i >= GF) return;
    int g = i >> 6;
    float c = fmaxf(cnt[g], 1.0f);
    pooled[i] = drop_scale(sums[i] / c, k0, k1, (u32)i);
}

__global__ void k_outgemm(const float* __restrict__ P, const float* __restrict__ Wl,
                          const float* __restrict__ bl, float* __restrict__ out,
                          int NG, int K, int O) {
    int i = blockIdx.x * blockDim.x + threadIdx.x;
    if (i >= NG * O) return;
    int g = i / O, o = i - g * O;
    float acc = bl[o];
    for (int k = 0; k < K; ++k) acc += P[g * K + k] * Wl[k * O + o];
    out[i] = acc;
}

// ---- launch ----------------------------------------------------------------
extern "C" void kernel_launch(void* const* d_in, const int* in_sizes, int n_in,
                              void* d_out, int out_size, void* d_ws, size_t ws_size,
                              hipStream_t stream) {
    const float* x  = (const float*)d_in[0];
    const void*  ei = d_in[1];
    const void*  bt = d_in[2];
    const float* W[3] = {(const float*)d_in[3], (const float*)d_in[5], (const float*)d_in[7]};
    const float* b[3] = {(const float*)d_in[4], (const float*)d_in[6], (const float*)d_in[8]};
    const float* Wl = (const float*)d_in[9];
    const float* bl = (const float*)d_in[10];
    float* out = (float*)d_out;

    const int F = 64;
    int N  = in_sizes[0] / F;      // 50000
    int E  = in_sizes[1] / 2;      // 800000
    int NG = 256;
    int O  = in_sizes[9] / F;      // 10
    long NF = (long)N * F;         // 3.2M
    int Np = ((N + 63) / 64) * 64;

    char* wp = (char*)d_ws;
    float* dinv   = (float*)wp;            wp += (size_t)Np * 4;
    int*   degi   = (int*)wp;              wp += (size_t)Np * 4;   // reused as cursor
    int*   offs   = (int*)wp;              wp += (size_t)(Np + 64) * 4;
    int*   part   = (int*)wp;              wp += 256 * 4;
    int*   flag   = (int*)wp;              wp += 64 * 4;
    float* sums   = (float*)wp;            wp += (size_t)NG * F * 4;
    float* cnt    = (float*)wp;            wp += (size_t)NG * 4;
    float* pooled = (float*)wp;            wp += (size_t)NG * F * 4;
    int2*  elist  = (int2*)wp;             wp += (size_t)E * 8;
    float* H      = (float*)wp;            wp += NF * 4;
    float* G      = (float*)wp;            wp += NF * 4;

    u32 dk[3][2];
    for (u32 i = 0; i < 3; ++i) tf2x32(0u, 12345u, 0u, i, &dk[i][0], &dk[i][1]);

    int P = (N + 255) / 256;   // scan blocks (196)

    k_detect<<<1, 64, 0, stream>>>((const u32*)ei, flag);
    hipMemsetAsync(degi, 0, (size_t)N * 4, stream);
    k_deg<<<(E + 255) / 256, 256, 0, stream>>>(ei, E, flag, degi);
    k_dinv<<<(N + 255) / 256, 256, 0, stream>>>(degi, dinv, N);
    k_scan_part<<<P, 256, 0, stream>>>(degi, offs, part, N);
    k_scan_mid<<<1, 256, 0, stream>>>(part, offs, P, N, E);
    k_scan_add<<<P, 256, 0, stream>>>(offs, part, degi /*cursor*/, N);
    k_bucket<<<(E + 255) / 256, 256, 0, stream>>>(ei, E, flag, dinv, degi, elist);

    int aggBlocks = (int)(((long)N * 64 + 255) / 256);
    for (int l = 0; l < 3; ++l) {
        const float* inp = (l == 0) ? x : G;
        k_gemm64<<<(N + 3) / 4, 256, 0, stream>>>(inp, W[l], H, N);
        k_agg<<<aggBlocks, 256, 0, stream>>>(elist, offs, dinv, H, b[l], G, N,
                                             (l < 2) ? 1 : 0, dk[l][0], dk[l][1]);
    }

    hipMemsetAsync(sums, 0, (size_t)(NG * F + NG) * 4, stream);
    int pw = (N + 7) / 8;  // waves
    k_poolsum<<<(int)(((long)pw * 64 + 255) / 256), 256, 0, stream>>>(G, bt, flag, N, sums, cnt);
    k_poolfin<<<(NG * F + 255) / 256, 256, 0, stream>>>(sums, cnt, pooled,
                                                        dk[2][0], dk[2][1], NG * F);
    k_outgemm<<<(NG * O + 255) / 256, 256, 0, stream>>>(pooled, Wl, bl, out, NG, F, O);
}

// Round 3
// 305.204 us; speedup vs baseline: 3.0201x; 1.2076x over previous
//
#include <hip/hip_runtime.h>

typedef unsigned int u32;
typedef unsigned short u16;

// ---- JAX threefry2x32 (20 rounds), bit-exact -------------------------------
__host__ __device__ inline void tf2x32(u32 k0, u32 k1, u32 x0, u32 x1,
                                       u32* y0, u32* y1) {
    u32 ks2 = k0 ^ k1 ^ 0x1BD11BDAu;
#define TFR(r) { x0 += x1; x1 = (x1 << (r)) | (x1 >> (32 - (r))); x1 ^= x0; }
    x0 += k0; x1 += k1;
    TFR(13) TFR(15) TFR(26) TFR(6)
    x0 += k1;  x1 += ks2 + 1u;
    TFR(17) TFR(29) TFR(16) TFR(24)
    x0 += ks2; x1 += k0 + 2u;
    TFR(13) TFR(15) TFR(26) TFR(6)
    x0 += k0;  x1 += k1 + 3u;
    TFR(17) TFR(29) TFR(16) TFR(24)
    x0 += k1;  x1 += ks2 + 4u;
    TFR(13) TFR(15) TFR(26) TFR(6)
    x0 += ks2; x1 += k0 + 5u;
#undef TFR
    *y0 = x0; *y1 = x1;
}

__device__ inline float drop_scale(float v, u32 k0, u32 k1, u32 idx) {
    u32 y0, y1;
    tf2x32(k0, k1, 0u, idx, &y0, &y1);
    u32 bits = y0 ^ y1;
    float u = __uint_as_float((bits >> 9) | 0x3f800000u) - 1.0f;
    return (u < 0.7f) ? (v / 0.7f) : 0.0f;
}

// bf16 helpers (RTN-even pack, simple unpack)
__device__ inline u16 f2bf(float f) {
    u32 u = __float_as_uint(f);
    u32 r = (u + 0x7fffu + ((u >> 16) & 1u)) >> 16;
    return (u16)r;
}
__device__ inline float bf2f(u16 h) {
    return __uint_as_float(((u32)h) << 16);
}

// ---- int32/int64 index handling --------------------------------------------
__global__ void k_detect(const u32* p, int* flag) {
    if (blockIdx.x == 0 && threadIdx.x == 0) {
        int all0 = 1;
        for (int i = 0; i < 64; ++i)
            if (p[2 * i + 1] != 0u) { all0 = 0; break; }
        *flag = all0;   // 1 => int64 layout
    }
}

__device__ inline int idx_at(const void* p, long i, int is64) {
    return is64 ? (int)((const long long*)p)[i] : ((const int*)p)[i];
}

// ---- CSR build -------------------------------------------------------------
__global__ void k_deg(const void* ei, int E, const int* flag, int* degi) {
    int e = blockIdx.x * blockDim.x + threadIdx.x;
    if (e >= E) return;
    atomicAdd(&degi[idx_at(ei, (long)E + e, *flag)], 1);
}

__global__ void k_dinv(const int* degi, float* dinv, int N) {
    int n = blockIdx.x * blockDim.x + threadIdx.x;
    if (n < N) dinv[n] = rsqrtf((float)degi[n] + 1.0f);
}

__global__ void k_scan_part(const int* degi, int* offs, int* part, int N) {
    __shared__ int s[256];
    int tid = threadIdx.x;
    int i = blockIdx.x * 256 + tid;
    int v = (i < N) ? degi[i] : 0;
    s[tid] = v; __syncthreads();
    for (int d = 1; d < 256; d <<= 1) {
        int t = (tid >= d) ? s[tid - d] : 0;
        __syncthreads();
        s[tid] += t;
        __syncthreads();
    }
    if (i < N) offs[i] = s[tid] - v;
    if (tid == 255) part[blockIdx.x] = s[255];
}

__global__ void k_scan_mid(int* part, int* offs, int P, int N, int E) {
    __shared__ int s[256];
    int tid = threadIdx.x;
    int v = (tid < P) ? part[tid] : 0;
    s[tid] = v; __syncthreads();
    for (int d = 1; d < 256; d <<= 1) {
        int t = (tid >= d) ? s[tid - d] : 0;
        __syncthreads();
        s[tid] += t;
        __syncthreads();
    }
    if (tid < P) part[tid] = s[tid] - v;  // exclusive
    if (tid == 0) offs[N] = E;
}

__global__ void k_scan_add(int* offs, const int* part, int* cursor, int N) {
    int i = blockIdx.x * 256 + threadIdx.x;
    if (i >= N) return;
    int v = offs[i] + part[blockIdx.x];
    offs[i] = v;
    cursor[i] = v;
}

__global__ void k_bucket(const void* ei, int E, const int* flag,
                         const float* __restrict__ dinv,
                         int* __restrict__ cursor, int2* __restrict__ elist) {
    int e = blockIdx.x * blockDim.x + threadIdx.x;
    if (e >= E) return;
    int is64 = *flag;
    int s = idx_at(ei, e, is64);
    int d = idx_at(ei, (long)E + e, is64);
    int pos = atomicAdd(&cursor[d], 1);
    int2 p; p.x = s; p.y = __float_as_int(dinv[s]);
    elist[pos] = p;
}

// ---- dense 64x64 GEMM: out = in @ W, bf16 output --------------------------
__global__ void k_gemm64(const float* __restrict__ in, const float* __restrict__ W,
                         u16* __restrict__ out, int N) {
    __shared__ float Ws[64 * 64];
    __shared__ float xs[4 * 64];
    int tid = threadIdx.x;
#pragma unroll
    for (int i = 0; i < 16; ++i) Ws[tid + i * 256] = W[tid + i * 256];
    int row0 = blockIdx.x * 4;
    long gi = (long)row0 * 64 + tid;
    xs[tid] = (gi < (long)N * 64) ? in[gi] : 0.0f;
    __syncthreads();
    int r = tid >> 6, c = tid & 63;
    int row = row0 + r;
    if (row >= N) return;
    float acc = 0.0f;
#pragma unroll
    for (int k = 0; k < 64; ++k) acc += xs[r * 64 + k] * Ws[k * 64 + c];
    out[(long)row * 64 + c] = f2bf(acc);
}

// ---- per-node aggregate: wave per node, shfl-broadcast edges, 4-way MLP ----
__global__ __launch_bounds__(256) void k_agg(
    const int2* __restrict__ elist, const int* __restrict__ offs,
    const float* __restrict__ dinv, const u16* __restrict__ Hb,
    const float* __restrict__ b, float* __restrict__ G,
    int N, int dodrop, u32 k0, u32 k1) {
    int node = (int)(((long)blockIdx.x * blockDim.x + threadIdx.x) >> 6);
    int f = threadIdx.x & 63;
    if (node >= N) return;
    int beg = offs[node], end = offs[node + 1];
    float acc0 = 0.0f, acc1 = 0.0f, acc2 = 0.0f, acc3 = 0.0f;
    for (int base = beg; base < end; base += 64) {
        int cnt = end - base; if (cnt > 64) cnt = 64;
        int2 my; my.x = 0; my.y = 0;
        if (base + f < end) my = elist[base + f];
        int j = 0;
        for (; j + 4 <= cnt; j += 4) {
            int   s0 = __shfl(my.x, j + 0);
            float w0 = __int_as_float(__shfl(my.y, j + 0));
            int   s1 = __shfl(my.x, j + 1);
            float w1 = __int_as_float(__shfl(my.y, j + 1));
            int   s2 = __shfl(my.x, j + 2);
            float w2 = __int_as_float(__shfl(my.y, j + 2));
            int   s3 = __shfl(my.x, j + 3);
            float w3 = __int_as_float(__shfl(my.y, j + 3));
            float h0 = bf2f(Hb[(long)s0 * 64 + f]);
            float h1 = bf2f(Hb[(long)s1 * 64 + f]);
            float h2 = bf2f(Hb[(long)s2 * 64 + f]);
            float h3 = bf2f(Hb[(long)s3 * 64 + f]);
            acc0 += w0 * h0; acc1 += w1 * h1; acc2 += w2 * h2; acc3 += w3 * h3;
        }
        for (; j < cnt; ++j) {
            int   s = __shfl(my.x, j);
            float w = __int_as_float(__shfl(my.y, j));
            acc0 += w * bf2f(Hb[(long)s * 64 + f]);
        }
    }
    float acc = (acc0 + acc1) + (acc2 + acc3);
    float di = dinv[node];
    float hn = bf2f(Hb[(long)node * 64 + f]);
    float v = di * acc + hn * di * di + b[f];
    if (dodrop) {
        v = fmaxf(v, 0.0f);
        v = drop_scale(v, k0, k1, (u32)(node * 64 + f));
    }
    G[(long)node * 64 + f] = v;
}

// ---- pooling ---------------------------------------------------------------
__global__ void k_poolsum(const float* __restrict__ G, const void* batch,
                          const int* flag, int N,
                          float* __restrict__ sums, float* __restrict__ cnt) {
    int wave = (int)(((long)blockIdx.x * blockDim.x + threadIdx.x) >> 6);
    int f = threadIdx.x & 63;
    int n0 = wave * 8;
    if (n0 >= N) return;
    int nend = n0 + 8 < N ? n0 + 8 : N;
    int is64 = *flag;
    float acc = 0.0f; float cacc = 0.0f; int curg = -1;
    for (int n = n0; n < nend; ++n) {
        int g = idx_at(batch, n, is64);
        if (g != curg) {
            if (curg >= 0) {
                atomicAdd(&sums[curg * 64 + f], acc);
                if (f == 0) atomicAdd(&cnt[curg], cacc);
            }
            curg = g; acc = 0.0f; cacc = 0.0f;
        }
        acc += G[(long)n * 64 + f];
        cacc += 1.0f;
    }
    if (curg >= 0) {
        atomicAdd(&sums[curg * 64 + f], acc);
        if (f == 0) atomicAdd(&cnt[curg], cacc);
    }
}

__global__ void k_poolfin(const float* __restrict__ sums, const float* __restrict__ cnt,
                          float* __restrict__ pooled, u32 k0, u32 k1, int GF) {
    int i = blockIdx.x * blockDim.x + threadIdx.x;
    if (i >= GF) return;
    int g = i >> 6;
    float c = fmaxf(cnt[g], 1.0f);
    pooled[i] = drop_scale(sums[i] / c, k0, k1, (u32)i);
}

__global__ void k_outgemm(const float* __restrict__ P, const float* __restrict__ Wl,
                          const float* __restrict__ bl, float* __restrict__ out,
                          int NG, int K, int O) {
    int i = blockIdx.x * blockDim.x + threadIdx.x;
    if (i >= NG * O) return;
    int g = i / O, o = i - g * O;
    float acc = bl[o];
    for (int k = 0; k < K; ++k) acc += P[g * K + k] * Wl[k * O + o];
    out[i] = acc;
}

// ---- launch ----------------------------------------------------------------
extern "C" void kernel_launch(void* const* d_in, const int* in_sizes, int n_in,
                              void* d_out, int out_size, void* d_ws, size_t ws_size,
                              hipStream_t stream) {
    const float* x  = (const float*)d_in[0];
    const void*  ei = d_in[1];
    const void*  bt = d_in[2];
    const float* W[3] = {(const float*)d_in[3], (const float*)d_in[5], (const float*)d_in[7]};
    const float* b[3] = {(const float*)d_in[4], (const float*)d_in[6], (const float*)d_in[8]};
    const float* Wl = (const float*)d_in[9];
    const float* bl = (const float*)d_in[10];
    float* out = (float*)d_out;

    const int F = 64;
    int N  = in_sizes[0] / F;      // 50000
    int E  = in_sizes[1] / 2;      // 800000
    int NG = 256;
    int O  = in_sizes[9] / F;      // 10
    long NF = (long)N * F;         // 3.2M
    int Np = ((N + 63) / 64) * 64;

    char* wp = (char*)d_ws;
    float* dinv   = (float*)wp;            wp += (size_t)Np * 4;
    int*   degi   = (int*)wp;              wp += (size_t)Np * 4;   // reused as cursor
    int*   offs   = (int*)wp;              wp += (size_t)(Np + 64) * 4;
    int*   part   = (int*)wp;              wp += 256 * 4;
    int*   flag   = (int*)wp;              wp += 64 * 4;
    float* sums   = (float*)wp;            wp += (size_t)NG * F * 4;
    float* cnt    = (float*)wp;            wp += (size_t)NG * 4;
    float* pooled = (float*)wp;            wp += (size_t)NG * F * 4;
    int2*  elist  = (int2*)wp;             wp += (size_t)E * 8;
    u16*   Hb     = (u16*)wp;              wp += NF * 2;
    float* G      = (float*)wp;            wp += NF * 4;

    u32 dk[3][2];
    for (u32 i = 0; i < 3; ++i) tf2x32(0u, 12345u, 0u, i, &dk[i][0], &dk[i][1]);

    int P = (N + 255) / 256;   // scan blocks

    k_detect<<<1, 64, 0, stream>>>((const u32*)ei, flag);
    hipMemsetAsync(degi, 0, (size_t)N * 4, stream);
    k_deg<<<(E + 255) / 256, 256, 0, stream>>>(ei, E, flag, degi);
    k_dinv<<<(N + 255) / 256, 256, 0, stream>>>(degi, dinv, N);
    k_scan_part<<<P, 256, 0, stream>>>(degi, offs, part, N);
    k_scan_mid<<<1, 256, 0, stream>>>(part, offs, P, N, E);
    k_scan_add<<<P, 256, 0, stream>>>(offs, part, degi /*cursor*/, N);
    k_bucket<<<(E + 255) / 256, 256, 0, stream>>>(ei, E, flag, dinv, degi, elist);

    int aggBlocks = (int)(((long)N * 64 + 255) / 256);
    for (int l = 0; l < 3; ++l) {
        const float* inp = (l == 0) ? x : G;
        k_gemm64<<<(N + 3) / 4, 256, 0, stream>>>(inp, W[l], Hb, N);
        k_agg<<<aggBlocks, 256, 0, stream>>>(elist, offs, dinv, Hb, b[l], G, N,
                                             (l < 2) ? 1 : 0, dk[l][0], dk[l][1]);
    }

    hipMemsetAsync(sums, 0, (size_t)(NG * F + NG) * 4, stream);
    int pw = (N + 7) / 8;  // waves
    k_poolsum<<<(int)(((long)pw * 64 + 255) / 256), 256, 0, stream>>>(G, bt, flag, N, sums, cnt);
    k_poolfin<<<(NG * F + 255) / 256, 256, 0, stream>>>(sums, cnt, pooled,
                                                        dk[2][0], dk[2][1], NG * F);
    k_outgemm<<<(NG * O + 255) / 256, 256, 0, stream>>>(pooled, Wl, bl, out, NG, F, O);
}

// Round 4
// 252.101 us; speedup vs baseline: 3.6562x; 1.2106x over previous
//
#include <hip/hip_runtime.h>

typedef unsigned int u32;
typedef unsigned short u16;
using bfrag  = __attribute__((ext_vector_type(8))) short;   // 8 bf16
using f32x4  = __attribute__((ext_vector_type(4))) float;   // MFMA acc

// ---- JAX threefry2x32 (20 rounds), bit-exact -------------------------------
__host__ __device__ inline void tf2x32(u32 k0, u32 k1, u32 x0, u32 x1,
                                       u32* y0, u32* y1) {
    u32 ks2 = k0 ^ k1 ^ 0x1BD11BDAu;
#define TFR(r) { x0 += x1; x1 = (x1 << (r)) | (x1 >> (32 - (r))); x1 ^= x0; }
    x0 += k0; x1 += k1;
    TFR(13) TFR(15) TFR(26) TFR(6)
    x0 += k1;  x1 += ks2 + 1u;
    TFR(17) TFR(29) TFR(16) TFR(24)
    x0 += ks2; x1 += k0 + 2u;
    TFR(13) TFR(15) TFR(26) TFR(6)
    x0 += k0;  x1 += k1 + 3u;
    TFR(17) TFR(29) TFR(16) TFR(24)
    x0 += k1;  x1 += ks2 + 4u;
    TFR(13) TFR(15) TFR(26) TFR(6)
    x0 += ks2; x1 += k0 + 5u;
#undef TFR
    *y0 = x0; *y1 = x1;
}

__device__ inline float drop_scale(float v, u32 k0, u32 k1, u32 idx) {
    u32 y0, y1;
    tf2x32(k0, k1, 0u, idx, &y0, &y1);
    u32 bits = y0 ^ y1;
    float u = __uint_as_float((bits >> 9) | 0x3f800000u) - 1.0f;
    return (u < 0.7f) ? (v / 0.7f) : 0.0f;
}

// bf16 helpers
__device__ inline u16 f2bf(float f) {
    u32 u = __float_as_uint(f);
    u32 r = (u + 0x7fffu + ((u >> 16) & 1u)) >> 16;
    return (u16)r;
}
__device__ inline float bf2f(u16 h) { return __uint_as_float(((u32)h) << 16); }

// ---- int32/int64 index handling --------------------------------------------
__global__ void k_detect(const u32* p, int* flag) {
    if (blockIdx.x == 0 && threadIdx.x == 0) {
        int all0 = 1;
        for (int i = 0; i < 64; ++i)
            if (p[2 * i + 1] != 0u) { all0 = 0; break; }
        *flag = all0;   // 1 => int64 layout
    }
}

__device__ inline int idx_at(const void* p, long i, int is64) {
    return is64 ? (int)((const long long*)p)[i] : ((const int*)p)[i];
}

// ---- CSR build -------------------------------------------------------------
__global__ void k_deg(const void* ei, int E, const int* flag, int* degi) {
    int e = blockIdx.x * blockDim.x + threadIdx.x;
    if (e >= E) return;
    atomicAdd(&degi[idx_at(ei, (long)E + e, *flag)], 1);
}

__global__ void k_dinv(const int* degi, float* dinv, int N) {
    int n = blockIdx.x * blockDim.x + threadIdx.x;
    if (n < N) dinv[n] = rsqrtf((float)degi[n] + 1.0f);
}

__global__ void k_scan_part(const int* degi, int* offs, int* part, int N) {
    __shared__ int s[256];
    int tid = threadIdx.x;
    int i = blockIdx.x * 256 + tid;
    int v = (i < N) ? degi[i] : 0;
    s[tid] = v; __syncthreads();
    for (int d = 1; d < 256; d <<= 1) {
        int t = (tid >= d) ? s[tid - d] : 0;
        __syncthreads();
        s[tid] += t;
        __syncthreads();
    }
    if (i < N) offs[i] = s[tid] - v;
    if (tid == 255) part[blockIdx.x] = s[255];
}

__global__ void k_scan_mid(int* part, int* offs, int P, int N, int E) {
    __shared__ int s[256];
    int tid = threadIdx.x;
    int v = (tid < P) ? part[tid] : 0;
    s[tid] = v; __syncthreads();
    for (int d = 1; d < 256; d <<= 1) {
        int t = (tid >= d) ? s[tid - d] : 0;
        __syncthreads();
        s[tid] += t;
        __syncthreads();
    }
    if (tid < P) part[tid] = s[tid] - v;  // exclusive
    if (tid == 0) offs[N] = E;
}

__global__ void k_scan_add(int* offs, const int* part, int* cursor, int N) {
    int i = blockIdx.x * 256 + threadIdx.x;
    if (i >= N) return;
    int v = offs[i] + part[blockIdx.x];
    offs[i] = v;
    cursor[i] = v;
}

__global__ void k_bucket(const void* ei, int E, const int* flag,
                         const float* __restrict__ dinv,
                         int* __restrict__ cursor, int2* __restrict__ elist) {
    int e = blockIdx.x * blockDim.x + threadIdx.x;
    if (e >= E) return;
    int is64 = *flag;
    int s = idx_at(ei, e, is64);
    int d = idx_at(ei, (long)E + e, is64);
    int pos = atomicAdd(&cursor[d], 1);
    int2 p; p.x = s; p.y = __float_as_int(dinv[s]);
    elist[pos] = p;
}

// ---- converts --------------------------------------------------------------
__global__ void k_cvt_x(const float* __restrict__ in, u16* __restrict__ out, long n4) {
    long i = (long)blockIdx.x * blockDim.x + threadIdx.x;
    if (i >= n4) return;
    float4 v = ((const float4*)in)[i];
    ushort4 o;
    o.x = f2bf(v.x); o.y = f2bf(v.y); o.z = f2bf(v.z); o.w = f2bf(v.w);
    ((ushort4*)out)[i] = o;
}

// W[64][64] f32 -> bf16 in MFMA B-fragment order:
// wsw[layer][((nt*2+ks)*64+lane)*8+j] = W[ks*32+(lane>>4)*8+j][nt*16+(lane&15)]
__global__ void k_cvt_w(const float* __restrict__ W0, const float* __restrict__ W1,
                        const float* __restrict__ W2, u16* __restrict__ wsw) {
    int t = blockIdx.x * 256 + threadIdx.x;
    if (t >= 3 * 4096) return;
    int layer = t >> 12, r = t & 4095;
    int nt = r >> 10, ks = (r >> 9) & 1, lane = (r >> 3) & 63, j = r & 7;
    const float* W = (layer == 0) ? W0 : ((layer == 1) ? W1 : W2);
    int k = ks * 32 + (lane >> 4) * 8 + j;
    int n = nt * 16 + (lane & 15);
    wsw[t] = f2bf(W[k * 64 + n]);
}

// ---- MFMA GEMM: H[N,64] = A[N,64] @ W ; 1 wave = 16 rows -------------------
__global__ __launch_bounds__(256) void k_gemm_mfma(
    const u16* __restrict__ A, const u16* __restrict__ Wsw,
    u16* __restrict__ Hout, int N) {
    int wid = blockIdx.x * 4 + (threadIdx.x >> 6);
    int lane = threadIdx.x & 63;
    int row0 = wid * 16;
    if (row0 >= N) return;
    int rl = lane & 15, kg = lane >> 4;
    int arow = row0 + rl; if (arow >= N) arow = N - 1;
    bfrag a0 = *(const bfrag*)(A + (long)arow * 64 + kg * 8);        // k 0..31
    bfrag a1 = *(const bfrag*)(A + (long)arow * 64 + 32 + kg * 8);   // k 32..63
#pragma unroll
    for (int nt = 0; nt < 4; ++nt) {
        bfrag b0 = *(const bfrag*)(Wsw + ((nt * 2 + 0) * 64 + lane) * 8);
        bfrag b1 = *(const bfrag*)(Wsw + ((nt * 2 + 1) * 64 + lane) * 8);
        f32x4 acc = {0.0f, 0.0f, 0.0f, 0.0f};
        acc = __builtin_amdgcn_mfma_f32_16x16x32_bf16(a0, b0, acc, 0, 0, 0);
        acc = __builtin_amdgcn_mfma_f32_16x16x32_bf16(a1, b1, acc, 0, 0, 0);
        int col = nt * 16 + rl;
#pragma unroll
        for (int i = 0; i < 4; ++i) {
            int row = row0 + kg * 4 + i;
            if (row < N) Hout[(long)row * 64 + col] = f2bf(acc[i]);
        }
    }
}

// ---- per-node aggregate: wave per node, shfl-broadcast, 8-way MLP ----------
__global__ __launch_bounds__(256) void k_agg(
    const int2* __restrict__ elist, const int* __restrict__ offs,
    const float* __restrict__ dinv, const u16* __restrict__ Hb,
    const float* __restrict__ b, u16* __restrict__ Gb, float* __restrict__ Gf,
    int N, int mode, u32 k0, u32 k1) {   // mode 1: relu+drop -> bf16; 0: f32
    int node = (int)(((long)blockIdx.x * blockDim.x + threadIdx.x) >> 6);
    int f = threadIdx.x & 63;
    if (node >= N) return;
    int beg = offs[node], end = offs[node + 1];
    float acc[8];
#pragma unroll
    for (int q = 0; q < 8; ++q) acc[q] = 0.0f;
    for (int base = beg; base < end; base += 64) {
        int cnt = end - base; if (cnt > 64) cnt = 64;
        int2 my; my.x = 0; my.y = 0;
        if (base + f < end) my = elist[base + f];
        int j = 0;
        for (; j + 8 <= cnt; j += 8) {
            int s_[8]; float w_[8], h_[8];
#pragma unroll
            for (int q = 0; q < 8; ++q) {
                s_[q] = __shfl(my.x, j + q);
                w_[q] = __int_as_float(__shfl(my.y, j + q));
            }
#pragma unroll
            for (int q = 0; q < 8; ++q) h_[q] = bf2f(Hb[(long)s_[q] * 64 + f]);
#pragma unroll
            for (int q = 0; q < 8; ++q) acc[q] += w_[q] * h_[q];
        }
        for (; j < cnt; ++j) {
            int s = __shfl(my.x, j);
            float w = __int_as_float(__shfl(my.y, j));
            acc[0] += w * bf2f(Hb[(long)s * 64 + f]);
        }
    }
    float a = ((acc[0] + acc[1]) + (acc[2] + acc[3])) +
              ((acc[4] + acc[5]) + (acc[6] + acc[7]));
    float di = dinv[node];
    float hn = bf2f(Hb[(long)node * 64 + f]);
    float v = di * a + hn * di * di + b[f];
    long idx = (long)node * 64 + f;
    if (mode) {
        v = fmaxf(v, 0.0f);
        v = drop_scale(v, k0, k1, (u32)idx);
        Gb[idx] = f2bf(v);
    } else {
        Gf[idx] = v;
    }
}

// ---- pooling ---------------------------------------------------------------
__global__ void k_poolsum(const float* __restrict__ G, const void* batch,
                          const int* flag, int N,
                          float* __restrict__ sums, float* __restrict__ cnt) {
    int wave = (int)(((long)blockIdx.x * blockDim.x + threadIdx.x) >> 6);
    int f = threadIdx.x & 63;
    int n0 = wave * 8;
    if (n0 >= N) return;
    int nend = n0 + 8 < N ? n0 + 8 : N;
    int is64 = *flag;
    float acc = 0.0f; float cacc = 0.0f; int curg = -1;
    for (int n = n0; n < nend; ++n) {
        int g = idx_at(batch, n, is64);
        if (g != curg) {
            if (curg >= 0) {
                atomicAdd(&sums[curg * 64 + f], acc);
                if (f == 0) atomicAdd(&cnt[curg], cacc);
            }
            curg = g; acc = 0.0f; cacc = 0.0f;
        }
        acc += G[(long)n * 64 + f];
        cacc += 1.0f;
    }
    if (curg >= 0) {
        atomicAdd(&sums[curg * 64 + f], acc);
        if (f == 0) atomicAdd(&cnt[curg], cacc);
    }
}

__global__ void k_poolfin(const float* __restrict__ sums, const float* __restrict__ cnt,
                          float* __restrict__ pooled, u32 k0, u32 k1, int GF) {
    int i = blockIdx.x * blockDim.x + threadIdx.x;
    if (i >= GF) return;
    int g = i >> 6;
    float c = fmaxf(cnt[g], 1.0f);
    pooled[i] = drop_scale(sums[i] / c, k0, k1, (u32)i);
}

__global__ void k_outgemm(const float* __restrict__ P, const float* __restrict__ Wl,
                          const float* __restrict__ bl, float* __restrict__ out,
                          int NG, int K, int O) {
    int i = blockIdx.x * blockDim.x + threadIdx.x;
    if (i >= NG * O) return;
    int g = i / O, o = i - g * O;
    float acc = bl[o];
    for (int k = 0; k < K; ++k) acc += P[g * K + k] * Wl[k * O + o];
    out[i] = acc;
}

// ---- launch ----------------------------------------------------------------
extern "C" void kernel_launch(void* const* d_in, const int* in_sizes, int n_in,
                              void* d_out, int out_size, void* d_ws, size_t ws_size,
                              hipStream_t stream) {
    const float* x  = (const float*)d_in[0];
    const void*  ei = d_in[1];
    const void*  bt = d_in[2];
    const float* W[3] = {(const float*)d_in[3], (const float*)d_in[5], (const float*)d_in[7]};
    const float* b[3] = {(const float*)d_in[4], (const float*)d_in[6], (const float*)d_in[8]};
    const float* Wl = (const float*)d_in[9];
    const float* bl = (const float*)d_in[10];
    float* out = (float*)d_out;

    const int F = 64;
    int N  = in_sizes[0] / F;      // 50000
    int E  = in_sizes[1] / 2;      // 800000
    int NG = 256;
    int O  = in_sizes[9] / F;      // 10
    long NF = (long)N * F;         // 3.2M
    int Np = ((N + 63) / 64) * 64;

    auto align256 = [](char*& p) { p = (char*)(((size_t)p + 255) & ~(size_t)255); };
    char* wp = (char*)d_ws;
    align256(wp); float* dinv   = (float*)wp;  wp += (size_t)Np * 4;
    align256(wp); int*   degi   = (int*)wp;    wp += (size_t)Np * 4;   // reused as cursor
    align256(wp); int*   offs   = (int*)wp;    wp += (size_t)(Np + 64) * 4;
    align256(wp); int*   part   = (int*)wp;    wp += 1024;
    align256(wp); int*   flag   = (int*)wp;    wp += 256;
    align256(wp); float* sums   = (float*)wp;  wp += (size_t)NG * F * 4;
    align256(wp); float* cnt    = (float*)wp;  wp += (size_t)NG * 4;
    align256(wp); float* pooled = (float*)wp;  wp += (size_t)NG * F * 4;
    align256(wp); u16*   wsw    = (u16*)wp;    wp += 3 * 4096 * 2;
    align256(wp); int2*  elist  = (int2*)wp;   wp += (size_t)E * 8;
    align256(wp); u16*   Hb     = (u16*)wp;    wp += NF * 2;
    // BUF1 aliases: xb(u16) -> Gb(u16, layers 0/1) -> G(f32, layer 2 + pool)
    align256(wp); char*  BUF1   = wp;          wp += NF * 4;
    u16*   Bb = (u16*)BUF1;
    float* Gf = (float*)BUF1;

    u32 dk[3][2];
    for (u32 i = 0; i < 3; ++i) tf2x32(0u, 12345u, 0u, i, &dk[i][0], &dk[i][1]);

    int P = (N + 255) / 256;   // scan blocks

    k_detect<<<1, 64, 0, stream>>>((const u32*)ei, flag);
    hipMemsetAsync(degi, 0, (size_t)N * 4, stream);
    k_deg<<<(E + 255) / 256, 256, 0, stream>>>(ei, E, flag, degi);
    k_dinv<<<(N + 255) / 256, 256, 0, stream>>>(degi, dinv, N);
    k_scan_part<<<P, 256, 0, stream>>>(degi, offs, part, N);
    k_scan_mid<<<1, 256, 0, stream>>>(part, offs, P, N, E);
    k_scan_add<<<P, 256, 0, stream>>>(offs, part, degi /*cursor*/, N);
    k_bucket<<<(E + 255) / 256, 256, 0, stream>>>(ei, E, flag, dinv, degi, elist);

    // converts
    long n4 = NF / 4;
    k_cvt_x<<<(int)((n4 + 255) / 256), 256, 0, stream>>>(x, Bb, n4);
    k_cvt_w<<<48, 256, 0, stream>>>(W[0], W[1], W[2], wsw);

    int gemmBlocks = ((N + 15) / 16 + 3) / 4;
    int aggBlocks = (int)(((long)N * 64 + 255) / 256);
    for (int l = 0; l < 3; ++l) {
        k_gemm_mfma<<<gemmBlocks, 256, 0, stream>>>(Bb, wsw + l * 4096, Hb, N);
        k_agg<<<aggBlocks, 256, 0, stream>>>(elist, offs, dinv, Hb, b[l],
                                             Bb, Gf, N, (l < 2) ? 1 : 0,
                                             dk[l][0], dk[l][1]);
    }

    hipMemsetAsync(sums, 0, (size_t)(NG * F + NG) * 4, stream);
    int pw = (N + 7) / 8;  // pooling waves
    k_poolsum<<<(int)(((long)pw * 64 + 255) / 256), 256, 0, stream>>>(Gf, bt, flag, N, sums, cnt);
    k_poolfin<<<(NG * F + 255) / 256, 256, 0, stream>>>(sums, cnt, pooled,
                                                        dk[2][0], dk[2][1], NG * F);
    k_outgemm<<<(NG * O + 255) / 256, 256, 0, stream>>>(pooled, Wl, bl, out, NG, F, O);
}

// Round 5
// 250.472 us; speedup vs baseline: 3.6800x; 1.0065x over previous
//
#include <hip/hip_runtime.h>

typedef unsigned int u32;
typedef unsigned short u16;
using bfrag  = __attribute__((ext_vector_type(8))) short;   // 8 bf16
using f32x4  = __attribute__((ext_vector_type(4))) float;   // MFMA acc

// ---- JAX threefry2x32 (20 rounds), bit-exact -------------------------------
__host__ __device__ inline void tf2x32(u32 k0, u32 k1, u32 x0, u32 x1,
                                       u32* y0, u32* y1) {
    u32 ks2 = k0 ^ k1 ^ 0x1BD11BDAu;
#define TFR(r) { x0 += x1; x1 = (x1 << (r)) | (x1 >> (32 - (r))); x1 ^= x0; }
    x0 += k0; x1 += k1;
    TFR(13) TFR(15) TFR(26) TFR(6)
    x0 += k1;  x1 += ks2 + 1u;
    TFR(17) TFR(29) TFR(16) TFR(24)
    x0 += ks2; x1 += k0 + 2u;
    TFR(13) TFR(15) TFR(26) TFR(6)
    x0 += k0;  x1 += k1 + 3u;
    TFR(17) TFR(29) TFR(16) TFR(24)
    x0 += k1;  x1 += ks2 + 4u;
    TFR(13) TFR(15) TFR(26) TFR(6)
    x0 += ks2; x1 += k0 + 5u;
#undef TFR
    *y0 = x0; *y1 = x1;
}

__device__ inline float drop_scale(float v, u32 k0, u32 k1, u32 idx) {
    u32 y0, y1;
    tf2x32(k0, k1, 0u, idx, &y0, &y1);
    u32 bits = y0 ^ y1;
    float u = __uint_as_float((bits >> 9) | 0x3f800000u) - 1.0f;
    return (u < 0.7f) ? (v / 0.7f) : 0.0f;
}

// bf16 helpers
__device__ inline u16 f2bf(float f) {
    u32 u = __float_as_uint(f);
    u32 r = (u + 0x7fffu + ((u >> 16) & 1u)) >> 16;
    return (u16)r;
}
__device__ inline float bf2f(u16 h) { return __uint_as_float(((u32)h) << 16); }

// ---- int32/int64 index handling --------------------------------------------
__global__ void k_detect(const u32* p, int* flag) {
    if (blockIdx.x == 0 && threadIdx.x == 0) {
        int all0 = 1;
        for (int i = 0; i < 64; ++i)
            if (p[2 * i + 1] != 0u) { all0 = 0; break; }
        *flag = all0;   // 1 => int64 layout
    }
}

__device__ inline int idx_at(const void* p, long i, int is64) {
    return is64 ? (int)((const long long*)p)[i] : ((const int*)p)[i];
}

// ---- degree + scan ---------------------------------------------------------
__global__ void k_deg(const void* ei, int E, const int* flag, int* degi) {
    int e = blockIdx.x * blockDim.x + threadIdx.x;
    if (e >= E) return;
    atomicAdd(&degi[idx_at(ei, (long)E + e, *flag)], 1);
}

__global__ void k_dinv(const int* degi, float* dinv, int N) {
    int n = blockIdx.x * blockDim.x + threadIdx.x;
    if (n < N) dinv[n] = rsqrtf((float)degi[n] + 1.0f);
}

__global__ void k_scan_part(const int* degi, int* offs, int* part, int N) {
    __shared__ int s[256];
    int tid = threadIdx.x;
    int i = blockIdx.x * 256 + tid;
    int v = (i < N) ? degi[i] : 0;
    s[tid] = v; __syncthreads();
    for (int d = 1; d < 256; d <<= 1) {
        int t = (tid >= d) ? s[tid - d] : 0;
        __syncthreads();
        s[tid] += t;
        __syncthreads();
    }
    if (i < N) offs[i] = s[tid] - v;
    if (tid == 255) part[blockIdx.x] = s[255];
}

__global__ void k_scan_mid(int* part, int* offs, int P, int N, int E) {
    __shared__ int s[256];
    int tid = threadIdx.x;
    int v = (tid < P) ? part[tid] : 0;
    s[tid] = v; __syncthreads();
    for (int d = 1; d < 256; d <<= 1) {
        int t = (tid >= d) ? s[tid - d] : 0;
        __syncthreads();
        s[tid] += t;
        __syncthreads();
    }
    if (tid < P) part[tid] = s[tid] - v;  // exclusive
    if (tid == 0) offs[N] = E;
}

__global__ void k_scan_add(int* offs, const int* part, int* cursor, int N) {
    int i = blockIdx.x * 256 + threadIdx.x;
    if (i >= N) return;
    int v = offs[i] + part[blockIdx.x];
    offs[i] = v;
    cursor[i] = v;
}

// bucket b covers nodes [b*512, (b+1)*512); its region base = offs[b*512]
__global__ void k_cur1(const int* offs, int* gCur1, int N, int NB) {
    int t = threadIdx.x;
    if (t < NB) gCur1[t] = offs[t << 9];
}

// ---- phase 1: LDS-binned scatter into bucket-contiguous binned[] -----------
#define CHUNK 4096
#define KPT 16
#define NBUCK 128

__global__ __launch_bounds__(256) void k_binscat(
    const void* ei, int E, const int* flag,
    int* __restrict__ gCur1, u32* __restrict__ binned) {
    __shared__ u32 stage[CHUNK];
    __shared__ int cnt[NBUCK], offsx[NBUCK], cur[NBUCK], gbase[NBUCK], scn[NBUCK];
    int tid = threadIdx.x;
    long base = (long)blockIdx.x * CHUNK;
    int is64 = *flag;
    if (tid < NBUCK) { cnt[tid] = 0; cur[tid] = 0; }
    __syncthreads();
    u32 rec[KPT];
#pragma unroll
    for (int k = 0; k < KPT; ++k) {
        long e = base + k * 256 + tid;
        u32 r = 0xFFFFFFFFu;
        if (e < E) {
            int s = idx_at(ei, e, is64);
            int d = idx_at(ei, (long)E + e, is64);
            r = ((u32)d << 16) | (u32)s;
            atomicAdd(&cnt[d >> 9], 1);
        }
        rec[k] = r;
    }
    __syncthreads();
    // exclusive scan of cnt (128 entries)
    if (tid < NBUCK) scn[tid] = cnt[tid];
    __syncthreads();
    for (int d = 1; d < NBUCK; d <<= 1) {
        int t2 = 0;
        if (tid < NBUCK && tid >= d) t2 = scn[tid - d];
        __syncthreads();
        if (tid < NBUCK) scn[tid] += t2;
        __syncthreads();
    }
    if (tid < NBUCK) offsx[tid] = scn[tid] - cnt[tid];
    __syncthreads();
    // place into stage (bucket-sorted)
#pragma unroll
    for (int k = 0; k < KPT; ++k) {
        u32 r = rec[k];
        if (r != 0xFFFFFFFFu) {
            int bk = r >> 25;
            int p = offsx[bk] + atomicAdd(&cur[bk], 1);
            stage[p] = r;
        }
    }
    __syncthreads();
    if (tid < NBUCK && cnt[tid] > 0)
        gbase[tid] = atomicAdd(&gCur1[tid], cnt[tid]);
    __syncthreads();
    int total = scn[NBUCK - 1];
    for (int i = tid; i < total; i += 256) {
        u32 r = stage[i];
        int bk = r >> 25;
        binned[gbase[bk] + (i - offsx[bk])] = r;
    }
}

// ---- phase 2: per-bucket exact CSR fill (u16 src), L2-local window ---------
__global__ __launch_bounds__(256) void k_csrfill(
    const u32* __restrict__ binned, const int* __restrict__ offs,
    int* __restrict__ cursor, u16* __restrict__ csr, int N) {
    int b = blockIdx.x;
    int n0 = b << 9;
    int n1 = n0 + 512; if (n1 > N) n1 = N;
    int beg = offs[n0], endb = offs[n1];
    for (int i = beg + threadIdx.x; i < endb; i += 256) {
        u32 r = binned[i];
        int d = r >> 16;
        int pos = atomicAdd(&cursor[d], 1);
        csr[pos] = (u16)(r & 0xFFFFu);
    }
}

// ---- converts --------------------------------------------------------------
__global__ void k_cvt_x(const float* __restrict__ in, u16* __restrict__ out, long n4) {
    long i = (long)blockIdx.x * blockDim.x + threadIdx.x;
    if (i >= n4) return;
    float4 v = ((const float4*)in)[i];
    ushort4 o;
    o.x = f2bf(v.x); o.y = f2bf(v.y); o.z = f2bf(v.z); o.w = f2bf(v.w);
    ((ushort4*)out)[i] = o;
}

// W[64][64] f32 -> bf16 in MFMA B-fragment order
__global__ void k_cvt_w(const float* __restrict__ W0, const float* __restrict__ W1,
                        const float* __restrict__ W2, u16* __restrict__ wsw) {
    int t = blockIdx.x * 256 + threadIdx.x;
    if (t >= 3 * 4096) return;
    int layer = t >> 12, r = t & 4095;
    int nt = r >> 10, ks = (r >> 9) & 1, lane = (r >> 3) & 63, j = r & 7;
    const float* W = (layer == 0) ? W0 : ((layer == 1) ? W1 : W2);
    int k = ks * 32 + (lane >> 4) * 8 + j;
    int n = nt * 16 + (lane & 15);
    wsw[t] = f2bf(W[k * 64 + n]);
}

// ---- MFMA GEMM: Hout[row] = bf16( dinv[row] * (A[row] @ W) ) ---------------
__global__ __launch_bounds__(256) void k_gemm_mfma(
    const u16* __restrict__ A, const u16* __restrict__ Wsw,
    const float* __restrict__ dinv, u16* __restrict__ Hout, int N) {
    int wid = blockIdx.x * 4 + (threadIdx.x >> 6);
    int lane = threadIdx.x & 63;
    int row0 = wid * 16;
    if (row0 >= N) return;
    int rl = lane & 15, kg = lane >> 4;
    int arow = row0 + rl; if (arow >= N) arow = N - 1;
    bfrag a0 = *(const bfrag*)(A + (long)arow * 64 + kg * 8);        // k 0..31
    bfrag a1 = *(const bfrag*)(A + (long)arow * 64 + 32 + kg * 8);   // k 32..63
    float d4[4];
#pragma unroll
    for (int i = 0; i < 4; ++i) {
        int row = row0 + kg * 4 + i;
        d4[i] = (row < N) ? dinv[row] : 0.0f;
    }
#pragma unroll
    for (int nt = 0; nt < 4; ++nt) {
        bfrag b0 = *(const bfrag*)(Wsw + ((nt * 2 + 0) * 64 + lane) * 8);
        bfrag b1 = *(const bfrag*)(Wsw + ((nt * 2 + 1) * 64 + lane) * 8);
        f32x4 acc = {0.0f, 0.0f, 0.0f, 0.0f};
        acc = __builtin_amdgcn_mfma_f32_16x16x32_bf16(a0, b0, acc, 0, 0, 0);
        acc = __builtin_amdgcn_mfma_f32_16x16x32_bf16(a1, b1, acc, 0, 0, 0);
        int col = nt * 16 + rl;
#pragma unroll
        for (int i = 0; i < 4; ++i) {
            int row = row0 + kg * 4 + i;
            if (row < N) Hout[(long)row * 64 + col] = f2bf(d4[i] * acc[i]);
        }
    }
}

// ---- per-node aggregate: wave/node, u16 csr, masked 8-wide -----------------
__global__ __launch_bounds__(256) void k_agg(
    const u16* __restrict__ csr, const int* __restrict__ offs,
    const float* __restrict__ dinv, const u16* __restrict__ Hb,
    const float* __restrict__ b, u16* __restrict__ Gb, float* __restrict__ Gf,
    int N, int mode, u32 k0, u32 k1) {   // mode 1: relu+drop -> bf16; 0: f32
    int node = (int)(((long)blockIdx.x * blockDim.x + threadIdx.x) >> 6);
    int f = threadIdx.x & 63;
    if (node >= N) return;
    int beg = offs[node], end = offs[node + 1];
    float acc[8];
#pragma unroll
    for (int q = 0; q < 8; ++q) acc[q] = 0.0f;
    for (int base = beg; base < end; base += 64) {
        int cnt = end - base; if (cnt > 64) cnt = 64;
        int my = (base + f < end) ? (int)csr[base + f] : 0;
        for (int j = 0; j < cnt; j += 8) {
            int s_[8]; float h_[8];
#pragma unroll
            for (int q = 0; q < 8; ++q) {
                int jj = j + q; if (jj >= cnt) jj = cnt - 1;   // uniform clamp
                s_[q] = __shfl(my, jj);
            }
#pragma unroll
            for (int q = 0; q < 8; ++q) h_[q] = bf2f(Hb[(long)s_[q] * 64 + f]);
#pragma unroll
            for (int q = 0; q < 8; ++q)
                acc[q] += (j + q < cnt) ? h_[q] : 0.0f;
        }
    }
    float a = ((acc[0] + acc[1]) + (acc[2] + acc[3])) +
              ((acc[4] + acc[5]) + (acc[6] + acc[7]));
    float di = dinv[node];
    float hn = bf2f(Hb[(long)node * 64 + f]);
    float v = di * (a + hn) + b[f];
    long idx = (long)node * 64 + f;
    if (mode) {
        v = fmaxf(v, 0.0f);
        v = drop_scale(v, k0, k1, (u32)idx);
        Gb[idx] = f2bf(v);
    } else {
        Gf[idx] = v;
    }
}

// ---- pooling ---------------------------------------------------------------
__global__ void k_poolsum(const float* __restrict__ G, const void* batch,
                          const int* flag, int N,
                          float* __restrict__ sums, float* __restrict__ cnt) {
    int wave = (int)(((long)blockIdx.x * blockDim.x + threadIdx.x) >> 6);
    int f = threadIdx.x & 63;
    int n0 = wave * 8;
    if (n0 >= N) return;
    int nend = n0 + 8 < N ? n0 + 8 : N;
    int is64 = *flag;
    float acc = 0.0f; float cacc = 0.0f; int curg = -1;
    for (int n = n0; n < nend; ++n) {
        int g = idx_at(batch, n, is64);
        if (g != curg) {
            if (curg >= 0) {
                atomicAdd(&sums[curg * 64 + f], acc);
                if (f == 0) atomicAdd(&cnt[curg], cacc);
            }
            curg = g; acc = 0.0f; cacc = 0.0f;
        }
        acc += G[(long)n * 64 + f];
        cacc += 1.0f;
    }
    if (curg >= 0) {
        atomicAdd(&sums[curg * 64 + f], acc);
        if (f == 0) atomicAdd(&cnt[curg], cacc);
    }
}

__global__ void k_poolfin(const float* __restrict__ sums, const float* __restrict__ cnt,
                          float* __restrict__ pooled, u32 k0, u32 k1, int GF) {
    int i = blockIdx.x * blockDim.x + threadIdx.x;
    if (i >= GF) return;
    int g = i >> 6;
    float c = fmaxf(cnt[g], 1.0f);
    pooled[i] = drop_scale(sums[i] / c, k0, k1, (u32)i);
}

__global__ void k_outgemm(const float* __restrict__ P, const float* __restrict__ Wl,
                          const float* __restrict__ bl, float* __restrict__ out,
                          int NG, int K, int O) {
    int i = blockIdx.x * blockDim.x + threadIdx.x;
    if (i >= NG * O) return;
    int g = i / O, o = i - g * O;
    float acc = bl[o];
    for (int k = 0; k < K; ++k) acc += P[g * K + k] * Wl[k * O + o];
    out[i] = acc;
}

// ---- launch ----------------------------------------------------------------
extern "C" void kernel_launch(void* const* d_in, const int* in_sizes, int n_in,
                              void* d_out, int out_size, void* d_ws, size_t ws_size,
                              hipStream_t stream) {
    const float* x  = (const float*)d_in[0];
    const void*  ei = d_in[1];
    const void*  bt = d_in[2];
    const float* W[3] = {(const float*)d_in[3], (const float*)d_in[5], (const float*)d_in[7]};
    const float* b[3] = {(const float*)d_in[4], (const float*)d_in[6], (const float*)d_in[8]};
    const float* Wl = (const float*)d_in[9];
    const float* bl = (const float*)d_in[10];
    float* out = (float*)d_out;

    const int F = 64;
    int N  = in_sizes[0] / F;      // 50000  (< 65536: u16 node ids)
    int E  = in_sizes[1] / 2;      // 800000
    int NG = 256;
    int O  = in_sizes[9] / F;      // 10
    long NF = (long)N * F;         // 3.2M
    int Np = ((N + 63) / 64) * 64;
    int NB = (N + 511) >> 9;       // coarse buckets (98)

    auto align256 = [](char*& p) { p = (char*)(((size_t)p + 255) & ~(size_t)255); };
    char* wp = (char*)d_ws;
    align256(wp); float* dinv   = (float*)wp;  wp += (size_t)Np * 4;
    align256(wp); int*   degi   = (int*)wp;    wp += (size_t)Np * 4;   // reused as cursor
    align256(wp); int*   offs   = (int*)wp;    wp += (size_t)(Np + 64) * 4;
    align256(wp); int*   part   = (int*)wp;    wp += 1024;
    align256(wp); int*   flag   = (int*)wp;    wp += 256;
    align256(wp); int*   gCur1  = (int*)wp;    wp += NBUCK * 4;
    align256(wp); float* sums   = (float*)wp;  wp += (size_t)NG * F * 4;
    align256(wp); float* cnt    = (float*)wp;  wp += (size_t)NG * 4;
    align256(wp); float* pooled = (float*)wp;  wp += (size_t)NG * F * 4;
    align256(wp); u16*   wsw    = (u16*)wp;    wp += 3 * 4096 * 2;
    align256(wp); u32*   binned = (u32*)wp;    wp += (size_t)E * 4;
    align256(wp); u16*   csr    = (u16*)wp;    wp += (size_t)E * 2;
    align256(wp); u16*   Hb     = (u16*)wp;    wp += NF * 2;
    // BUF1 aliases: xb/Gb (u16, layers 0/1) -> Gf (f32, layer 2 + pool)
    align256(wp); char*  BUF1   = wp;          wp += NF * 4;
    u16*   Bb = (u16*)BUF1;
    float* Gf = (float*)BUF1;

    u32 dk[3][2];
    for (u32 i = 0; i < 3; ++i) tf2x32(0u, 12345u, 0u, i, &dk[i][0], &dk[i][1]);

    int P = (N + 255) / 256;   // scan blocks

    k_detect<<<1, 64, 0, stream>>>((const u32*)ei, flag);
    hipMemsetAsync(degi, 0, (size_t)N * 4, stream);
    k_deg<<<(E + 255) / 256, 256, 0, stream>>>(ei, E, flag, degi);
    k_dinv<<<(N + 255) / 256, 256, 0, stream>>>(degi, dinv, N);
    k_scan_part<<<P, 256, 0, stream>>>(degi, offs, part, N);
    k_scan_mid<<<1, 256, 0, stream>>>(part, offs, P, N, E);
    k_scan_add<<<P, 256, 0, stream>>>(offs, part, degi /*cursor*/, N);
    k_cur1<<<1, 128, 0, stream>>>(offs, gCur1, N, NB);
    k_binscat<<<(E + CHUNK - 1) / CHUNK, 256, 0, stream>>>(ei, E, flag, gCur1, binned);
    k_csrfill<<<NB, 256, 0, stream>>>(binned, offs, degi /*cursor*/, csr, N);

    // converts
    long n4 = NF / 4;
    k_cvt_x<<<(int)((n4 + 255) / 256), 256, 0, stream>>>(x, Bb, n4);
    k_cvt_w<<<48, 256, 0, stream>>>(W[0], W[1], W[2], wsw);

    int gemmBlocks = ((N + 15) / 16 + 3) / 4;
    int aggBlocks = (int)(((long)N * 64 + 255) / 256);
    for (int l = 0; l < 3; ++l) {
        k_gemm_mfma<<<gemmBlocks, 256, 0, stream>>>(Bb, wsw + l * 4096, dinv, Hb, N);
        k_agg<<<aggBlocks, 256, 0, stream>>>(csr, offs, dinv, Hb, b[l],
                                             Bb, Gf, N, (l < 2) ? 1 : 0,
                                             dk[l][0], dk[l][1]);
    }

    hipMemsetAsync(sums, 0, (size_t)(NG * F + NG) * 4, stream);
    int pw = (N + 7) / 8;  // pooling waves
    k_poolsum<<<(int)(((long)pw * 64 + 255) / 256), 256, 0, stream>>>(Gf, bt, flag, N, sums, cnt);
    k_poolfin<<<(NG * F + 255) / 256, 256, 0, stream>>>(sums, cnt, pooled,
                                                        dk[2][0], dk[2][1], NG * F);
    k_outgemm<<<(NG * O + 255) / 256, 256, 0, stream>>>(pooled, Wl, bl, out, NG, F, O);
}

// Round 6
// 229.141 us; speedup vs baseline: 4.0226x; 1.0931x over previous
//
#include <hip/hip_runtime.h>

typedef unsigned int u32;
typedef unsigned short u16;
using bfrag  = __attribute__((ext_vector_type(8))) short;   // 8 bf16
using f32x4  = __attribute__((ext_vector_type(4))) float;   // MFMA acc

// ---- JAX threefry2x32 (20 rounds), bit-exact -------------------------------
__host__ __device__ inline void tf2x32(u32 k0, u32 k1, u32 x0, u32 x1,
                                       u32* y0, u32* y1) {
    u32 ks2 = k0 ^ k1 ^ 0x1BD11BDAu;
#define TFR(r) { x0 += x1; x1 = (x1 << (r)) | (x1 >> (32 - (r))); x1 ^= x0; }
    x0 += k0; x1 += k1;
    TFR(13) TFR(15) TFR(26) TFR(6)
    x0 += k1;  x1 += ks2 + 1u;
    TFR(17) TFR(29) TFR(16) TFR(24)
    x0 += ks2; x1 += k0 + 2u;
    TFR(13) TFR(15) TFR(26) TFR(6)
    x0 += k0;  x1 += k1 + 3u;
    TFR(17) TFR(29) TFR(16) TFR(24)
    x0 += k1;  x1 += ks2 + 4u;
    TFR(13) TFR(15) TFR(26) TFR(6)
    x0 += ks2; x1 += k0 + 5u;
#undef TFR
    *y0 = x0; *y1 = x1;
}

__device__ inline float drop_scale(float v, u32 k0, u32 k1, u32 idx) {
    u32 y0, y1;
    tf2x32(k0, k1, 0u, idx, &y0, &y1);
    u32 bits = y0 ^ y1;
    float u = __uint_as_float((bits >> 9) | 0x3f800000u) - 1.0f;
    return (u < 0.7f) ? (v / 0.7f) : 0.0f;
}

// bf16 helpers
__device__ inline u16 f2bf(float f) {
    u32 u = __float_as_uint(f);
    u32 r = (u + 0x7fffu + ((u >> 16) & 1u)) >> 16;
    return (u16)r;
}
__device__ inline float bf2f(u16 h) { return __uint_as_float(((u32)h) << 16); }

// ---- int32/int64 index handling --------------------------------------------
__global__ void k_detect(const u32* p, int* flag) {
    if (blockIdx.x == 0 && threadIdx.x == 0) {
        int all0 = 1;
        for (int i = 0; i < 64; ++i)
            if (p[2 * i + 1] != 0u) { all0 = 0; break; }
        *flag = all0;   // 1 => int64 layout
    }
}

__device__ inline int idx_at(const void* p, long i, int is64) {
    return is64 ? (int)((const long long*)p)[i] : ((const int*)p)[i];
}

// ---- degree + scan ---------------------------------------------------------
__global__ void k_deg(const void* ei, int E, const int* flag, int* degi) {
    int e = blockIdx.x * blockDim.x + threadIdx.x;
    if (e >= E) return;
    atomicAdd(&degi[idx_at(ei, (long)E + e, *flag)], 1);
}

__global__ void k_dinv(const int* degi, float* dinv, int N) {
    int n = blockIdx.x * blockDim.x + threadIdx.x;
    if (n < N) dinv[n] = rsqrtf((float)degi[n] + 1.0f);
}

__global__ void k_scan_part(const int* degi, int* offs, int* part, int N) {
    __shared__ int s[256];
    int tid = threadIdx.x;
    int i = blockIdx.x * 256 + tid;
    int v = (i < N) ? degi[i] : 0;
    s[tid] = v; __syncthreads();
    for (int d = 1; d < 256; d <<= 1) {
        int t = (tid >= d) ? s[tid - d] : 0;
        __syncthreads();
        s[tid] += t;
        __syncthreads();
    }
    if (i < N) offs[i] = s[tid] - v;
    if (tid == 255) part[blockIdx.x] = s[255];
}

__global__ void k_scan_mid(int* part, int* offs, int P, int N, int E) {
    __shared__ int s[256];
    int tid = threadIdx.x;
    int v = (tid < P) ? part[tid] : 0;
    s[tid] = v; __syncthreads();
    for (int d = 1; d < 256; d <<= 1) {
        int t = (tid >= d) ? s[tid - d] : 0;
        __syncthreads();
        s[tid] += t;
        __syncthreads();
    }
    if (tid < P) part[tid] = s[tid] - v;  // exclusive
    if (tid == 0) offs[N] = E;
}

__global__ void k_scan_add(int* offs, const int* part, int* cursor, int N) {
    int i = blockIdx.x * 256 + threadIdx.x;
    if (i >= N) return;
    int v = offs[i] + part[blockIdx.x];
    offs[i] = v;
    cursor[i] = v;
}

// bucket b covers nodes [b*512, (b+1)*512); its region base = offs[b*512]
__global__ void k_cur1(const int* offs, int* gCur1, int N, int NB) {
    int t = threadIdx.x;
    if (t < NB) gCur1[t] = offs[t << 9];
}

// ---- phase 1: LDS-binned scatter into bucket-contiguous binned[] -----------
#define CHUNK 4096
#define KPT 16
#define NBUCK 128

__global__ __launch_bounds__(256) void k_binscat(
    const void* ei, int E, const int* flag,
    int* __restrict__ gCur1, u32* __restrict__ binned) {
    __shared__ u32 stage[CHUNK];
    __shared__ int cnt[NBUCK], offsx[NBUCK], cur[NBUCK], gbase[NBUCK], scn[NBUCK];
    int tid = threadIdx.x;
    long base = (long)blockIdx.x * CHUNK;
    int is64 = *flag;
    if (tid < NBUCK) { cnt[tid] = 0; cur[tid] = 0; }
    __syncthreads();
    u32 rec[KPT];
#pragma unroll
    for (int k = 0; k < KPT; ++k) {
        long e = base + k * 256 + tid;
        u32 r = 0xFFFFFFFFu;
        if (e < E) {
            int s = idx_at(ei, e, is64);
            int d = idx_at(ei, (long)E + e, is64);
            r = ((u32)d << 16) | (u32)s;
            atomicAdd(&cnt[d >> 9], 1);
        }
        rec[k] = r;
    }
    __syncthreads();
    // exclusive scan of cnt (128 entries)
    if (tid < NBUCK) scn[tid] = cnt[tid];
    __syncthreads();
    for (int d = 1; d < NBUCK; d <<= 1) {
        int t2 = 0;
        if (tid < NBUCK && tid >= d) t2 = scn[tid - d];
        __syncthreads();
        if (tid < NBUCK) scn[tid] += t2;
        __syncthreads();
    }
    if (tid < NBUCK) offsx[tid] = scn[tid] - cnt[tid];
    __syncthreads();
    // place into stage (bucket-sorted)
#pragma unroll
    for (int k = 0; k < KPT; ++k) {
        u32 r = rec[k];
        if (r != 0xFFFFFFFFu) {
            int bk = r >> 25;
            int p = offsx[bk] + atomicAdd(&cur[bk], 1);
            stage[p] = r;
        }
    }
    __syncthreads();
    if (tid < NBUCK && cnt[tid] > 0)
        gbase[tid] = atomicAdd(&gCur1[tid], cnt[tid]);
    __syncthreads();
    int total = scn[NBUCK - 1];
    for (int i = tid; i < total; i += 256) {
        u32 r = stage[i];
        int bk = r >> 25;
        binned[gbase[bk] + (i - offsx[bk])] = r;
    }
}

// ---- phase 2: per-bucket exact CSR fill (u16 src), L2-local window ---------
__global__ __launch_bounds__(256) void k_csrfill(
    const u32* __restrict__ binned, const int* __restrict__ offs,
    int* __restrict__ cursor, u16* __restrict__ csr, int N) {
    int b = blockIdx.x;
    int n0 = b << 9;
    int n1 = n0 + 512; if (n1 > N) n1 = N;
    int beg = offs[n0], endb = offs[n1];
    for (int i = beg + threadIdx.x; i < endb; i += 256) {
        u32 r = binned[i];
        int d = r >> 16;
        int pos = atomicAdd(&cursor[d], 1);
        csr[pos] = (u16)(r & 0xFFFFu);
    }
}

// ---- converts --------------------------------------------------------------
// W[64][64] f32 -> bf16 in MFMA B-fragment order
__global__ void k_cvt_w(const float* __restrict__ W0, const float* __restrict__ W1,
                        const float* __restrict__ W2, u16* __restrict__ wsw) {
    int t = blockIdx.x * 256 + threadIdx.x;
    if (t >= 3 * 4096) return;
    int layer = t >> 12, r = t & 4095;
    int nt = r >> 10, ks = (r >> 9) & 1, lane = (r >> 3) & 63, j = r & 7;
    const float* W = (layer == 0) ? W0 : ((layer == 1) ? W1 : W2);
    int k = ks * 32 + (lane >> 4) * 8 + j;
    int n = nt * 16 + (lane & 15);
    wsw[t] = f2bf(W[k * 64 + n]);
}

// ---- MFMA GEMM: Hout[row] = bf16( dinv[row] * (A[row] @ W) ) ---------------
// use_f32 != 0: read f32 input Af (layer 0); else bf16 Ab.
__global__ __launch_bounds__(256) void k_gemm_mfma(
    const u16* __restrict__ Ab, const float* __restrict__ Af,
    const u16* __restrict__ Wsw, const float* __restrict__ dinv,
    u16* __restrict__ Hout, int N, int use_f32) {
    int wid = blockIdx.x * 4 + (threadIdx.x >> 6);
    int lane = threadIdx.x & 63;
    int row0 = wid * 16;
    if (row0 >= N) return;
    int rl = lane & 15, kg = lane >> 4;
    int arow = row0 + rl; if (arow >= N) arow = N - 1;
    bfrag a0, a1;
    if (use_f32) {
        const float* r = Af + (long)arow * 64 + kg * 8;
        float4 v0 = *(const float4*)(r);
        float4 v1 = *(const float4*)(r + 4);
        float4 v2 = *(const float4*)(r + 32);
        float4 v3 = *(const float4*)(r + 36);
        a0[0] = (short)f2bf(v0.x); a0[1] = (short)f2bf(v0.y);
        a0[2] = (short)f2bf(v0.z); a0[3] = (short)f2bf(v0.w);
        a0[4] = (short)f2bf(v1.x); a0[5] = (short)f2bf(v1.y);
        a0[6] = (short)f2bf(v1.z); a0[7] = (short)f2bf(v1.w);
        a1[0] = (short)f2bf(v2.x); a1[1] = (short)f2bf(v2.y);
        a1[2] = (short)f2bf(v2.z); a1[3] = (short)f2bf(v2.w);
        a1[4] = (short)f2bf(v3.x); a1[5] = (short)f2bf(v3.y);
        a1[6] = (short)f2bf(v3.z); a1[7] = (short)f2bf(v3.w);
    } else {
        a0 = *(const bfrag*)(Ab + (long)arow * 64 + kg * 8);
        a1 = *(const bfrag*)(Ab + (long)arow * 64 + 32 + kg * 8);
    }
    float d4[4];
#pragma unroll
    for (int i = 0; i < 4; ++i) {
        int row = row0 + kg * 4 + i;
        d4[i] = (row < N) ? dinv[row] : 0.0f;
    }
#pragma unroll
    for (int nt = 0; nt < 4; ++nt) {
        bfrag b0 = *(const bfrag*)(Wsw + ((nt * 2 + 0) * 64 + lane) * 8);
        bfrag b1 = *(const bfrag*)(Wsw + ((nt * 2 + 1) * 64 + lane) * 8);
        f32x4 acc = {0.0f, 0.0f, 0.0f, 0.0f};
        acc = __builtin_amdgcn_mfma_f32_16x16x32_bf16(a0, b0, acc, 0, 0, 0);
        acc = __builtin_amdgcn_mfma_f32_16x16x32_bf16(a1, b1, acc, 0, 0, 0);
        int col = nt * 16 + rl;
#pragma unroll
        for (int i = 0; i < 4; ++i) {
            int row = row0 + kg * 4 + i;
            if (row < N) Hout[(long)row * 64 + col] = f2bf(d4[i] * acc[i]);
        }
    }
}

// ---- per-node aggregate: wave/node, 16-lane teams, 4 edges per load --------
__global__ __launch_bounds__(256) void k_agg(
    const u16* __restrict__ csr, const int* __restrict__ offs,
    const float* __restrict__ dinv, const u16* __restrict__ Hb,
    const float* __restrict__ b, u16* __restrict__ Gb, float* __restrict__ Gf,
    int N, int mode, u32 k0, u32 k1) {   // mode 1: relu+drop -> bf16; 0: f32
    int node = (int)(((long)blockIdx.x * blockDim.x + threadIdx.x) >> 6);
    int lane = threadIdx.x & 63;
    if (node >= N) return;
    int t = lane >> 4;        // team 0..3 (edge slot)
    int q = lane & 15;        // features 4q .. 4q+3
    int beg = offs[node], end = offs[node + 1];
    float a0 = 0.0f, a1 = 0.0f, a2 = 0.0f, a3 = 0.0f;
    for (int base = beg; base < end; base += 64) {
        int cnt = end - base; if (cnt > 64) cnt = 64;
        int my = (lane < cnt) ? (int)csr[base + lane] : 0;
        for (int g = 0; g < cnt; g += 16) {
#pragma unroll
            for (int u = 0; u < 4; ++u) {
                int j = g + u * 4 + t;               // this team's edge
                int src = __shfl(my, j & 63);        // 0 if masked below
                uint2 d = *(const uint2*)(Hb + ((long)src << 6) + (q << 2));
                float m = (j < cnt) ? 1.0f : 0.0f;
                a0 += m * __uint_as_float(d.x << 16);
                a1 += m * __uint_as_float(d.x & 0xffff0000u);
                a2 += m * __uint_as_float(d.y << 16);
                a3 += m * __uint_as_float(d.y & 0xffff0000u);
            }
        }
    }
    // combine the 4 teams' partials (lanes q, q+16, q+32, q+48)
    a0 += __shfl_xor(a0, 16); a1 += __shfl_xor(a1, 16);
    a2 += __shfl_xor(a2, 16); a3 += __shfl_xor(a3, 16);
    a0 += __shfl_xor(a0, 32); a1 += __shfl_xor(a1, 32);
    a2 += __shfl_xor(a2, 32); a3 += __shfl_xor(a3, 32);
    int f = (q << 2) + t;                            // this lane's output feat
    float av = (t == 0) ? a0 : (t == 1) ? a1 : (t == 2) ? a2 : a3;
    float di = dinv[node];
    float hn = bf2f(Hb[((long)node << 6) + f]);
    float v = di * (av + hn) + b[f];
    long idx = ((long)node << 6) + f;
    if (mode) {
        v = fmaxf(v, 0.0f);
        v = drop_scale(v, k0, k1, (u32)idx);
        Gb[idx] = f2bf(v);
    } else {
        Gf[idx] = v;
    }
}

// ---- pooling ---------------------------------------------------------------
__global__ void k_poolsum(const float* __restrict__ G, const void* batch,
                          const int* flag, int N,
                          float* __restrict__ sums, float* __restrict__ cnt) {
    int wave = (int)(((long)blockIdx.x * blockDim.x + threadIdx.x) >> 6);
    int f = threadIdx.x & 63;
    int n0 = wave * 8;
    if (n0 >= N) return;
    int nend = n0 + 8 < N ? n0 + 8 : N;
    int is64 = *flag;
    float acc = 0.0f; float cacc = 0.0f; int curg = -1;
    for (int n = n0; n < nend; ++n) {
        int g = idx_at(batch, n, is64);
        if (g != curg) {
            if (curg >= 0) {
                atomicAdd(&sums[curg * 64 + f], acc);
                if (f == 0) atomicAdd(&cnt[curg], cacc);
            }
            curg = g; acc = 0.0f; cacc = 0.0f;
        }
        acc += G[(long)n * 64 + f];
        cacc += 1.0f;
    }
    if (curg >= 0) {
        atomicAdd(&sums[curg * 64 + f], acc);
        if (f == 0) atomicAdd(&cnt[curg], cacc);
    }
}

__global__ void k_poolfin(const float* __restrict__ sums, const float* __restrict__ cnt,
                          float* __restrict__ pooled, u32 k0, u32 k1, int GF) {
    int i = blockIdx.x * blockDim.x + threadIdx.x;
    if (i >= GF) return;
    int g = i >> 6;
    float c = fmaxf(cnt[g], 1.0f);
    pooled[i] = drop_scale(sums[i] / c, k0, k1, (u32)i);
}

__global__ void k_outgemm(const float* __restrict__ P, const float* __restrict__ Wl,
                          const float* __restrict__ bl, float* __restrict__ out,
                          int NG, int K, int O) {
    int i = blockIdx.x * blockDim.x + threadIdx.x;
    if (i >= NG * O) return;
    int g = i / O, o = i - g * O;
    float acc = bl[o];
    for (int k = 0; k < K; ++k) acc += P[g * K + k] * Wl[k * O + o];
    out[i] = acc;
}

// ---- launch ----------------------------------------------------------------
extern "C" void kernel_launch(void* const* d_in, const int* in_sizes, int n_in,
                              void* d_out, int out_size, void* d_ws, size_t ws_size,
                              hipStream_t stream) {
    const float* x  = (const float*)d_in[0];
    const void*  ei = d_in[1];
    const void*  bt = d_in[2];
    const float* W[3] = {(const float*)d_in[3], (const float*)d_in[5], (const float*)d_in[7]};
    const float* b[3] = {(const float*)d_in[4], (const float*)d_in[6], (const float*)d_in[8]};
    const float* Wl = (const float*)d_in[9];
    const float* bl = (const float*)d_in[10];
    float* out = (float*)d_out;

    const int F = 64;
    int N  = in_sizes[0] / F;      // 50000  (< 65536: u16 node ids)
    int E  = in_sizes[1] / 2;      // 800000
    int NG = 256;
    int O  = in_sizes[9] / F;      // 10
    long NF = (long)N * F;         // 3.2M
    int Np = ((N + 63) / 64) * 64;
    int NB = (N + 511) >> 9;       // coarse buckets (98)

    auto align256 = [](char*& p) { p = (char*)(((size_t)p + 255) & ~(size_t)255); };
    char* wp = (char*)d_ws;
    align256(wp); float* dinv   = (float*)wp;  wp += (size_t)Np * 4;
    align256(wp); int*   degi   = (int*)wp;    wp += (size_t)Np * 4;   // reused as cursor
    align256(wp); int*   offs   = (int*)wp;    wp += (size_t)(Np + 64) * 4;
    align256(wp); int*   part   = (int*)wp;    wp += 1024;
    align256(wp); int*   flag   = (int*)wp;    wp += 256;
    align256(wp); int*   gCur1  = (int*)wp;    wp += NBUCK * 4;
    align256(wp); float* sums   = (float*)wp;  wp += (size_t)NG * F * 4;
    align256(wp); float* cnt    = (float*)wp;  wp += (size_t)NG * 4;
    align256(wp); float* pooled = (float*)wp;  wp += (size_t)NG * F * 4;
    align256(wp); u16*   wsw    = (u16*)wp;    wp += 3 * 4096 * 2;
    align256(wp); u32*   binned = (u32*)wp;    wp += (size_t)E * 4;
    align256(wp); u16*   csr    = (u16*)wp;    wp += (size_t)E * 2;
    align256(wp); u16*   Hb     = (u16*)wp;    wp += NF * 2;
    // BUF1 aliases: Gb (u16, layers 0/1 out) / Gf (f32, layer 2 out + pool in)
    align256(wp); char*  BUF1   = wp;          wp += NF * 4;
    u16*   Gb = (u16*)BUF1;
    float* Gf = (float*)BUF1;

    u32 dk[3][2];
    for (u32 i = 0; i < 3; ++i) tf2x32(0u, 12345u, 0u, i, &dk[i][0], &dk[i][1]);

    int P = (N + 255) / 256;   // scan blocks

    k_detect<<<1, 64, 0, stream>>>((const u32*)ei, flag);
    hipMemsetAsync(degi, 0, (size_t)N * 4, stream);
    k_deg<<<(E + 255) / 256, 256, 0, stream>>>(ei, E, flag, degi);
    k_dinv<<<(N + 255) / 256, 256, 0, stream>>>(degi, dinv, N);
    k_scan_part<<<P, 256, 0, stream>>>(degi, offs, part, N);
    k_scan_mid<<<1, 256, 0, stream>>>(part, offs, P, N, E);
    k_scan_add<<<P, 256, 0, stream>>>(offs, part, degi /*cursor*/, N);
    k_cur1<<<1, 128, 0, stream>>>(offs, gCur1, N, NB);
    k_binscat<<<(E + CHUNK - 1) / CHUNK, 256, 0, stream>>>(ei, E, flag, gCur1, binned);
    k_csrfill<<<NB, 256, 0, stream>>>(binned, offs, degi /*cursor*/, csr, N);

    k_cvt_w<<<48, 256, 0, stream>>>(W[0], W[1], W[2], wsw);

    int gemmBlocks = ((N + 15) / 16 + 3) / 4;
    int aggBlocks = (int)(((long)N * 64 + 255) / 256);
    for (int l = 0; l < 3; ++l) {
        k_gemm_mfma<<<gemmBlocks, 256, 0, stream>>>(Gb, x, wsw + l * 4096, dinv,
                                                    Hb, N, (l == 0) ? 1 : 0);
        k_agg<<<aggBlocks, 256, 0, stream>>>(csr, offs, dinv, Hb, b[l],
                                             Gb, Gf, N, (l < 2) ? 1 : 0,
                                             dk[l][0], dk[l][1]);
    }

    hipMemsetAsync(sums, 0, (size_t)(NG * F + NG) * 4, stream);
    int pw = (N + 7) / 8;  // pooling waves
    k_poolsum<<<(int)(((long)pw * 64 + 255) / 256), 256, 0, stream>>>(Gf, bt, flag, N, sums, cnt);
    k_poolfin<<<(NG * F + 255) / 256, 256, 0, stream>>>(sums, cnt, pooled,
                                                        dk[2][0], dk[2][1], NG * F);
    k_outgemm<<<(NG * O + 255) / 256, 256, 0, stream>>>(pooled, Wl, bl, out, NG, F, O);
}

// Round 7
// 185.670 us; speedup vs baseline: 4.9644x; 1.2341x over previous
//
#include <hip/hip_runtime.h>

typedef unsigned int u32;
typedef unsigned short u16;
using bfrag  = __attribute__((ext_vector_type(8))) short;   // 8 bf16
using f32x4  = __attribute__((ext_vector_type(4))) float;   // MFMA acc

#define CHUNK 4096
#define KPT 16
#define NBUCK 128

// ---- JAX threefry2x32 (20 rounds), bit-exact -------------------------------
__host__ __device__ inline void tf2x32(u32 k0, u32 k1, u32 x0, u32 x1,
                                       u32* y0, u32* y1) {
    u32 ks2 = k0 ^ k1 ^ 0x1BD11BDAu;
#define TFR(r) { x0 += x1; x1 = (x1 << (r)) | (x1 >> (32 - (r))); x1 ^= x0; }
    x0 += k0; x1 += k1;
    TFR(13) TFR(15) TFR(26) TFR(6)
    x0 += k1;  x1 += ks2 + 1u;
    TFR(17) TFR(29) TFR(16) TFR(24)
    x0 += ks2; x1 += k0 + 2u;
    TFR(13) TFR(15) TFR(26) TFR(6)
    x0 += k0;  x1 += k1 + 3u;
    TFR(17) TFR(29) TFR(16) TFR(24)
    x0 += k1;  x1 += ks2 + 4u;
    TFR(13) TFR(15) TFR(26) TFR(6)
    x0 += ks2; x1 += k0 + 5u;
#undef TFR
    *y0 = x0; *y1 = x1;
}

__device__ inline float drop_scale(float v, u32 k0, u32 k1, u32 idx) {
    u32 y0, y1;
    tf2x32(k0, k1, 0u, idx, &y0, &y1);
    u32 bits = y0 ^ y1;
    float u = __uint_as_float((bits >> 9) | 0x3f800000u) - 1.0f;
    return (u < 0.7f) ? (v / 0.7f) : 0.0f;
}

// bf16 helpers
__device__ inline u16 f2bf(float f) {
    u32 u = __float_as_uint(f);
    u32 r = (u + 0x7fffu + ((u >> 16) & 1u)) >> 16;
    return (u16)r;
}
__device__ inline float bf2f(u16 h) { return __uint_as_float(((u32)h) << 16); }

// ---- int32/int64 index handling --------------------------------------------
__global__ void k_detect(const u32* p, int* flag) {
    if (blockIdx.x == 0 && threadIdx.x == 0) {
        int all0 = 1;
        for (int i = 0; i < 64; ++i)
            if (p[2 * i + 1] != 0u) { all0 = 0; break; }
        *flag = all0;   // 1 => int64 layout
    }
}

__device__ inline int idx_at(const void* p, long i, int is64) {
    return is64 ? (int)((const long long*)p)[i] : ((const int*)p)[i];
}

// ---- bucket counts (LDS-aggregated) ----------------------------------------
__global__ __launch_bounds__(256) void k_bcnt(const void* ei, int E,
                                              const int* flag, int* __restrict__ gCnt) {
    __shared__ int c[NBUCK];
    int tid = threadIdx.x;
    if (tid < NBUCK) c[tid] = 0;
    __syncthreads();
    int is64 = *flag;
    long base = (long)blockIdx.x * CHUNK + tid;
#pragma unroll
    for (int k = 0; k < KPT; ++k) {
        long e = base + k * 256;
        if (e < E) atomicAdd(&c[idx_at(ei, (long)E + e, is64) >> 9], 1);
    }
    __syncthreads();
    if (tid < NBUCK && c[tid]) atomicAdd(&gCnt[tid], c[tid]);
}

// 128-wide exclusive scan -> bucket bases (raw), init binscat cursors
__global__ void k_bscan(const int* __restrict__ gCnt, int* __restrict__ bbase,
                        int* __restrict__ gCur1) {
    __shared__ int s[NBUCK];
    int tid = threadIdx.x;           // 128 threads
    int v = gCnt[tid];
    s[tid] = v; __syncthreads();
    for (int d = 1; d < NBUCK; d <<= 1) {
        int t = (tid >= d) ? s[tid - d] : 0;
        __syncthreads();
        s[tid] += t;
        __syncthreads();
    }
    int excl = s[tid] - v;
    bbase[tid] = excl;
    gCur1[tid] = excl;
    if (tid == NBUCK - 1) bbase[NBUCK] = s[tid];
}

// ---- phase 1: LDS-binned scatter into bucket-contiguous binned[] -----------
__global__ __launch_bounds__(256) void k_binscat(
    const void* ei, int E, const int* flag,
    int* __restrict__ gCur1, u32* __restrict__ binned) {
    __shared__ u32 stage[CHUNK];
    __shared__ int cnt[NBUCK], offsx[NBUCK], cur[NBUCK], gbase[NBUCK], scn[NBUCK];
    int tid = threadIdx.x;
    long base = (long)blockIdx.x * CHUNK;
    int is64 = *flag;
    if (tid < NBUCK) { cnt[tid] = 0; cur[tid] = 0; }
    __syncthreads();
    u32 rec[KPT];
#pragma unroll
    for (int k = 0; k < KPT; ++k) {
        long e = base + k * 256 + tid;
        u32 r = 0xFFFFFFFFu;
        if (e < E) {
            int s = idx_at(ei, e, is64);
            int d = idx_at(ei, (long)E + e, is64);
            r = ((u32)d << 16) | (u32)s;
            atomicAdd(&cnt[d >> 9], 1);
        }
        rec[k] = r;
    }
    __syncthreads();
    if (tid < NBUCK) scn[tid] = cnt[tid];
    __syncthreads();
    for (int d = 1; d < NBUCK; d <<= 1) {
        int t2 = 0;
        if (tid < NBUCK && tid >= d) t2 = scn[tid - d];
        __syncthreads();
        if (tid < NBUCK) scn[tid] += t2;
        __syncthreads();
    }
    if (tid < NBUCK) offsx[tid] = scn[tid] - cnt[tid];
    __syncthreads();
#pragma unroll
    for (int k = 0; k < KPT; ++k) {
        u32 r = rec[k];
        if (r != 0xFFFFFFFFu) {
            int bk = r >> 25;
            int p = offsx[bk] + atomicAdd(&cur[bk], 1);
            stage[p] = r;
        }
    }
    __syncthreads();
    if (tid < NBUCK && cnt[tid] > 0)
        gbase[tid] = atomicAdd(&gCur1[tid], cnt[tid]);
    __syncthreads();
    int total = scn[NBUCK - 1];
    for (int i = tid; i < total; i += 256) {
        u32 r = stage[i];
        int bk = r >> 25;
        binned[gbase[bk] + (i - offsx[bk])] = r;
    }
}

// ---- phase 2 (fused): per-node counts, padded offsets, dinv, csr fill ------
// csr segments per node padded to multiples of 8 entries (16B-aligned).
__global__ __launch_bounds__(512) void k_csrfill(
    const u32* __restrict__ binned, const int* __restrict__ bbase,
    int* __restrict__ offs, int* __restrict__ degi, float* __restrict__ dinv,
    u16* __restrict__ csr, int N) {
    __shared__ int lcnt[512];
    __shared__ int lcur[512];
    int b = blockIdx.x;
    int n0 = b << 9;
    int nn = N - n0; if (nn > 512) nn = 512;
    int tid = threadIdx.x;
    lcnt[tid] = 0;
    __syncthreads();
    int rbeg = bbase[b], rend = bbase[b + 1];
    for (int i = rbeg + tid; i < rend; i += 512)
        atomicAdd(&lcnt[(int)(binned[i] >> 16) - n0], 1);
    __syncthreads();
    int v = lcnt[tid];              // raw degree
    int pv = (v + 7) & ~7;          // padded
    __syncthreads();
    lcnt[tid] = pv;
    __syncthreads();
    for (int d = 1; d < 512; d <<= 1) {
        int t2 = (tid >= d) ? lcnt[tid - d] : 0;
        __syncthreads();
        lcnt[tid] += t2;
        __syncthreads();
    }
    int pexcl = lcnt[tid] - pv;
    int pbase = bbase[b] + (b << 12);    // raw base + worst-case pad slack
    int o = pbase + pexcl;
    if (tid < nn) {
        offs[n0 + tid] = o;
        degi[n0 + tid] = v;
        dinv[n0 + tid] = rsqrtf((float)v + 1.0f);
        lcur[tid] = o;
    }
    __syncthreads();
    for (int i = rbeg + tid; i < rend; i += 512) {
        u32 r = binned[i];
        int pos = atomicAdd(&lcur[(int)(r >> 16) - n0], 1);
        csr[pos] = (u16)(r & 0xFFFFu);
    }
}

// ---- converts --------------------------------------------------------------
__global__ void k_cvt_w(const float* __restrict__ W0, const float* __restrict__ W1,
                        const float* __restrict__ W2, u16* __restrict__ wsw) {
    int t = blockIdx.x * 256 + threadIdx.x;
    if (t >= 3 * 4096) return;
    int layer = t >> 12, r = t & 4095;
    int nt = r >> 10, ks = (r >> 9) & 1, lane = (r >> 3) & 63, j = r & 7;
    const float* W = (layer == 0) ? W0 : ((layer == 1) ? W1 : W2);
    int k = ks * 32 + (lane >> 4) * 8 + j;
    int n = nt * 16 + (lane & 15);
    wsw[t] = f2bf(W[k * 64 + n]);
}

// ---- MFMA GEMM: Hout[row] = bf16( dinv[row] * (A[row] @ W) ) ---------------
__global__ __launch_bounds__(256) void k_gemm_mfma(
    const u16* __restrict__ Ab, const float* __restrict__ Af,
    const u16* __restrict__ Wsw, const float* __restrict__ dinv,
    u16* __restrict__ Hout, int N, int use_f32) {
    int wid = blockIdx.x * 4 + (threadIdx.x >> 6);
    int lane = threadIdx.x & 63;
    int row0 = wid * 16;
    if (row0 >= N) return;
    int rl = lane & 15, kg = lane >> 4;
    int arow = row0 + rl; if (arow >= N) arow = N - 1;
    bfrag a0, a1;
    if (use_f32) {
        const float* r = Af + (long)arow * 64 + kg * 8;
        float4 v0 = *(const float4*)(r);
        float4 v1 = *(const float4*)(r + 4);
        float4 v2 = *(const float4*)(r + 32);
        float4 v3 = *(const float4*)(r + 36);
        a0[0] = (short)f2bf(v0.x); a0[1] = (short)f2bf(v0.y);
        a0[2] = (short)f2bf(v0.z); a0[3] = (short)f2bf(v0.w);
        a0[4] = (short)f2bf(v1.x); a0[5] = (short)f2bf(v1.y);
        a0[6] = (short)f2bf(v1.z); a0[7] = (short)f2bf(v1.w);
        a1[0] = (short)f2bf(v2.x); a1[1] = (short)f2bf(v2.y);
        a1[2] = (short)f2bf(v2.z); a1[3] = (short)f2bf(v2.w);
        a1[4] = (short)f2bf(v3.x); a1[5] = (short)f2bf(v3.y);
        a1[6] = (short)f2bf(v3.z); a1[7] = (short)f2bf(v3.w);
    } else {
        a0 = *(const bfrag*)(Ab + (long)arow * 64 + kg * 8);
        a1 = *(const bfrag*)(Ab + (long)arow * 64 + 32 + kg * 8);
    }
    float d4[4];
#pragma unroll
    for (int i = 0; i < 4; ++i) {
        int row = row0 + kg * 4 + i;
        d4[i] = (row < N) ? dinv[row] : 0.0f;
    }
#pragma unroll
    for (int nt = 0; nt < 4; ++nt) {
        bfrag b0 = *(const bfrag*)(Wsw + ((nt * 2 + 0) * 64 + lane) * 8);
        bfrag b1 = *(const bfrag*)(Wsw + ((nt * 2 + 1) * 64 + lane) * 8);
        f32x4 acc = {0.0f, 0.0f, 0.0f, 0.0f};
        acc = __builtin_amdgcn_mfma_f32_16x16x32_bf16(a0, b0, acc, 0, 0, 0);
        acc = __builtin_amdgcn_mfma_f32_16x16x32_bf16(a1, b1, acc, 0, 0, 0);
        int col = nt * 16 + rl;
#pragma unroll
        for (int i = 0; i < 4; ++i) {
            int row = row0 + kg * 4 + i;
            if (row < N) Hout[(long)row * 64 + col] = f2bf(d4[i] * acc[i]);
        }
    }
}

// ---- per-node aggregate: 16-lane teams, aligned ushort4 id loads, 8-deep ---
__global__ __launch_bounds__(256) void k_agg(
    const u16* __restrict__ csr, const int* __restrict__ offs,
    const int* __restrict__ degi, const float* __restrict__ dinv,
    const u16* __restrict__ Hb, const float* __restrict__ b,
    u16* __restrict__ Gb, float* __restrict__ Gf,
    int N, int mode, u32 k0, u32 k1) {   // mode 1: relu+drop -> bf16; 0: f32
    int node = (int)(((long)blockIdx.x * blockDim.x + threadIdx.x) >> 6);
    int lane = threadIdx.x & 63;
    if (node >= N) return;
    int t = lane >> 4;        // team 0..3 (8-edge slice per 32-block)
    int q = lane & 15;        // feature quad: feats 4q..4q+3
    int beg = offs[node];     // 8-aligned
    int deg = degi[node];
    float a0 = 0.0f, a1 = 0.0f, a2 = 0.0f, a3 = 0.0f;
    int toff = t << 3;
    for (int g = 0; g < deg; g += 32) {
        int rem = deg - g;
        if (toff < rem) {
            const u16* cp = csr + beg + g + toff;
            ushort4 cA = *(const ushort4*)cp;        // aligned: beg%8==0
            ushort4 cB = *(const ushort4*)(cp + 4);
            u16 ids[8] = {cA.x, cA.y, cA.z, cA.w, cB.x, cB.y, cB.z, cB.w};
            int tcnt = rem - toff;                   // valid for this team
#pragma unroll
            for (int u = 0; u < 8; ++u) {
                uint2 d = *(const uint2*)(Hb + ((long)ids[u] << 6) + (q << 2));
                u32 dx = (u < tcnt) ? d.x : 0u;
                u32 dy = (u < tcnt) ? d.y : 0u;
                a0 += __uint_as_float(dx << 16);
                a1 += __uint_as_float(dx & 0xffff0000u);
                a2 += __uint_as_float(dy << 16);
                a3 += __uint_as_float(dy & 0xffff0000u);
            }
        }
    }
    // combine the 4 teams' partials (lanes q, q+16, q+32, q+48)
    a0 += __shfl_xor(a0, 16); a1 += __shfl_xor(a1, 16);
    a2 += __shfl_xor(a2, 16); a3 += __shfl_xor(a3, 16);
    a0 += __shfl_xor(a0, 32); a1 += __shfl_xor(a1, 32);
    a2 += __shfl_xor(a2, 32); a3 += __shfl_xor(a3, 32);
    int f = (q << 2) + t;
    float av = (t == 0) ? a0 : (t == 1) ? a1 : (t == 2) ? a2 : a3;
    float di = dinv[node];
    float hn = bf2f(Hb[((long)node << 6) + f]);
    float v = di * (av + hn) + b[f];
    long idx = ((long)node << 6) + f;
    if (mode) {
        v = fmaxf(v, 0.0f);
        v = drop_scale(v, k0, k1, (u32)idx);
        Gb[idx] = f2bf(v);
    } else {
        Gf[idx] = v;
    }
}

// ---- pooling ---------------------------------------------------------------
__global__ void k_poolsum(const float* __restrict__ G, const void* batch,
                          const int* flag, int N,
                          float* __restrict__ sums, float* __restrict__ cnt) {
    int wave = (int)(((long)blockIdx.x * blockDim.x + threadIdx.x) >> 6);
    int f = threadIdx.x & 63;
    int n0 = wave * 8;
    if (n0 >= N) return;
    int nend = n0 + 8 < N ? n0 + 8 : N;
    int is64 = *flag;
    float acc = 0.0f; float cacc = 0.0f; int curg = -1;
    for (int n = n0; n < nend; ++n) {
        int g = idx_at(batch, n, is64);
        if (g != curg) {
            if (curg >= 0) {
                atomicAdd(&sums[curg * 64 + f], acc);
                if (f == 0) atomicAdd(&cnt[curg], cacc);
            }
            curg = g; acc = 0.0f; cacc = 0.0f;
        }
        acc += G[(long)n * 64 + f];
        cacc += 1.0f;
    }
    if (curg >= 0) {
        atomicAdd(&sums[curg * 64 + f], acc);
        if (f == 0) atomicAdd(&cnt[curg], cacc);
    }
}

__global__ void k_poolfin(const float* __restrict__ sums, const float* __restrict__ cnt,
                          float* __restrict__ pooled, u32 k0, u32 k1, int GF) {
    int i = blockIdx.x * blockDim.x + threadIdx.x;
    if (i >= GF) return;
    int g = i >> 6;
    float c = fmaxf(cnt[g], 1.0f);
    pooled[i] = drop_scale(sums[i] / c, k0, k1, (u32)i);
}

__global__ void k_outgemm(const float* __restrict__ P, const float* __restrict__ Wl,
                          const float* __restrict__ bl, float* __restrict__ out,
                          int NG, int K, int O) {
    int i = blockIdx.x * blockDim.x + threadIdx.x;
    if (i >= NG * O) return;
    int g = i / O, o = i - g * O;
    float acc = bl[o];
    for (int k = 0; k < K; ++k) acc += P[g * K + k] * Wl[k * O + o];
    out[i] = acc;
}

// ---- launch ----------------------------------------------------------------
extern "C" void kernel_launch(void* const* d_in, const int* in_sizes, int n_in,
                              void* d_out, int out_size, void* d_ws, size_t ws_size,
                              hipStream_t stream) {
    const float* x  = (const float*)d_in[0];
    const void*  ei = d_in[1];
    const void*  bt = d_in[2];
    const float* W[3] = {(const float*)d_in[3], (const float*)d_in[5], (const float*)d_in[7]};
    const float* b[3] = {(const float*)d_in[4], (const float*)d_in[6], (const float*)d_in[8]};
    const float* Wl = (const float*)d_in[9];
    const float* bl = (const float*)d_in[10];
    float* out = (float*)d_out;

    const int F = 64;
    int N  = in_sizes[0] / F;      // 50000  (< 65536: u16 node ids)
    int E  = in_sizes[1] / 2;      // 800000
    int NG = 256;
    int O  = in_sizes[9] / F;      // 10
    long NF = (long)N * F;         // 3.2M
    int Np = ((N + 63) / 64) * 64;
    int NB = (N + 511) >> 9;       // coarse buckets (98)

    auto align256 = [](char*& p) { p = (char*)(((size_t)p + 255) & ~(size_t)255); };
    char* wp = (char*)d_ws;
    align256(wp); float* dinv   = (float*)wp;  wp += (size_t)Np * 4;
    align256(wp); int*   degi   = (int*)wp;    wp += (size_t)Np * 4;
    align256(wp); int*   offs   = (int*)wp;    wp += (size_t)(Np + 64) * 4;
    align256(wp); int*   flag   = (int*)wp;    wp += 256;
    align256(wp); int*   gCnt   = (int*)wp;    wp += NBUCK * 4;
    align256(wp); int*   bbase  = (int*)wp;    wp += (NBUCK + 64) * 4;
    align256(wp); int*   gCur1  = (int*)wp;    wp += NBUCK * 4;
    align256(wp); float* sums   = (float*)wp;  wp += (size_t)NG * F * 4;
    align256(wp); float* cnt    = (float*)wp;  wp += (size_t)NG * 4;
    align256(wp); float* pooled = (float*)wp;  wp += (size_t)NG * F * 4;
    align256(wp); u16*   wsw    = (u16*)wp;    wp += 3 * 4096 * 2;
    align256(wp); u32*   binned = (u32*)wp;    wp += (size_t)E * 4;
    align256(wp); u16*   csr    = (u16*)wp;    wp += ((size_t)E + (size_t)NBUCK * 4096 + 64) * 2;
    align256(wp); u16*   Hb     = (u16*)wp;    wp += NF * 2;
    // BUF1 aliases: Gb (u16, layers 0/1 out) / Gf (f32, layer 2 out + pool in)
    align256(wp); char*  BUF1   = wp;          wp += NF * 4;
    u16*   Gb = (u16*)BUF1;
    float* Gf = (float*)BUF1;

    u32 dk[3][2];
    for (u32 i = 0; i < 3; ++i) tf2x32(0u, 12345u, 0u, i, &dk[i][0], &dk[i][1]);

    int EB = (E + CHUNK - 1) / CHUNK;   // 196 edge-chunk blocks

    k_detect<<<1, 64, 0, stream>>>((const u32*)ei, flag);
    hipMemsetAsync(gCnt, 0, NBUCK * 4, stream);
    k_bcnt<<<EB, 256, 0, stream>>>(ei, E, flag, gCnt);
    k_bscan<<<1, NBUCK, 0, stream>>>(gCnt, bbase, gCur1);
    k_binscat<<<EB, 256, 0, stream>>>(ei, E, flag, gCur1, binned);
    k_csrfill<<<NB, 512, 0, stream>>>(binned, bbase, offs, degi, dinv, csr, N);

    k_cvt_w<<<48, 256, 0, stream>>>(W[0], W[1], W[2], wsw);

    int gemmBlocks = ((N + 15) / 16 + 3) / 4;
    int aggBlocks = (int)(((long)N * 64 + 255) / 256);
    for (int l = 0; l < 3; ++l) {
        k_gemm_mfma<<<gemmBlocks, 256, 0, stream>>>(Gb, x, wsw + l * 4096, dinv,
                                                    Hb, N, (l == 0) ? 1 : 0);
        k_agg<<<aggBlocks, 256, 0, stream>>>(csr, offs, degi, dinv, Hb, b[l],
                                             Gb, Gf, N, (l < 2) ? 1 : 0,
                                             dk[l][0], dk[l][1]);
    }

    hipMemsetAsync(sums, 0, (size_t)(NG * F + NG) * 4, stream);
    int pw = (N + 7) / 8;  // pooling waves
    k_poolsum<<<(int)(((long)pw * 64 + 255) / 256), 256, 0, stream>>>(Gf, bt, flag, N, sums, cnt);
    k_poolfin<<<(NG * F + 255) / 256, 256, 0, stream>>>(sums, cnt, pooled,
                                                        dk[2][0], dk[2][1], NG * F);
    k_outgemm<<<(NG * O + 255) / 256, 256, 0, stream>>>(pooled, Wl, bl, out, NG, F, O);
}

// Round 8
// 175.086 us; speedup vs baseline: 5.2645x; 1.0605x over previous
//
#include <hip/hip_runtime.h>

typedef unsigned int u32;
typedef unsigned short u16;
using bfrag  = __attribute__((ext_vector_type(8))) short;   // 8 bf16
using f32x4  = __attribute__((ext_vector_type(4))) float;   // MFMA acc

#define CHUNK 4096
#define KPT 16
#define NBUCK 128

// ---- JAX threefry2x32 (20 rounds), bit-exact -------------------------------
__host__ __device__ inline void tf2x32(u32 k0, u32 k1, u32 x0, u32 x1,
                                       u32* y0, u32* y1) {
    u32 ks2 = k0 ^ k1 ^ 0x1BD11BDAu;
#define TFR(r) { x0 += x1; x1 = (x1 << (r)) | (x1 >> (32 - (r))); x1 ^= x0; }
    x0 += k0; x1 += k1;
    TFR(13) TFR(15) TFR(26) TFR(6)
    x0 += k1;  x1 += ks2 + 1u;
    TFR(17) TFR(29) TFR(16) TFR(24)
    x0 += ks2; x1 += k0 + 2u;
    TFR(13) TFR(15) TFR(26) TFR(6)
    x0 += k0;  x1 += k1 + 3u;
    TFR(17) TFR(29) TFR(16) TFR(24)
    x0 += k1;  x1 += ks2 + 4u;
    TFR(13) TFR(15) TFR(26) TFR(6)
    x0 += ks2; x1 += k0 + 5u;
#undef TFR
    *y0 = x0; *y1 = x1;
}

__device__ inline float drop_scale(float v, u32 k0, u32 k1, u32 idx) {
    u32 y0, y1;
    tf2x32(k0, k1, 0u, idx, &y0, &y1);
    u32 bits = y0 ^ y1;
    float u = __uint_as_float((bits >> 9) | 0x3f800000u) - 1.0f;
    return (u < 0.7f) ? (v / 0.7f) : 0.0f;
}

// bf16 helpers
__device__ inline u16 f2bf(float f) {
    u32 u = __float_as_uint(f);
    u32 r = (u + 0x7fffu + ((u >> 16) & 1u)) >> 16;
    return (u16)r;
}
__device__ inline float bf2f(u16 h) { return __uint_as_float(((u32)h) << 16); }

// ---- int32/int64 detect + zero gCnt ----------------------------------------
__global__ void k_detect(const u32* p, int* flag, int* gCnt) {
    int tid = threadIdx.x;                 // 128 threads
    if (tid < NBUCK) gCnt[tid] = 0;
    if (tid == 0) {
        int all0 = 1;
        for (int i = 0; i < 64; ++i)
            if (p[2 * i + 1] != 0u) { all0 = 0; break; }
        *flag = all0;   // 1 => int64 layout
    }
}

__device__ inline int idx_at(const void* p, long i, int is64) {
    return is64 ? (int)((const long long*)p)[i] : ((const int*)p)[i];
}

// ---- bucket counts (LDS-aggregated) ----------------------------------------
__global__ __launch_bounds__(256) void k_bcnt(const void* ei, int E,
                                              const int* flag, int* __restrict__ gCnt) {
    __shared__ int c[NBUCK];
    int tid = threadIdx.x;
    if (tid < NBUCK) c[tid] = 0;
    __syncthreads();
    int is64 = *flag;
    long base = (long)blockIdx.x * CHUNK + tid;
#pragma unroll
    for (int k = 0; k < KPT; ++k) {
        long e = base + k * 256;
        if (e < E) atomicAdd(&c[idx_at(ei, (long)E + e, is64) >> 9], 1);
    }
    __syncthreads();
    if (tid < NBUCK && c[tid]) atomicAdd(&gCnt[tid], c[tid]);
}

// 128-wide exclusive scan -> bucket bases; also zero sums+cnt (pool buffers)
__global__ void k_bscan(const int* __restrict__ gCnt, int* __restrict__ bbase,
                        int* __restrict__ gCur1, float* __restrict__ sums, int ZN) {
    __shared__ int s[NBUCK];
    int tid = threadIdx.x;           // 128 threads
    int v = gCnt[tid];
    s[tid] = v; __syncthreads();
    for (int d = 1; d < NBUCK; d <<= 1) {
        int t = (tid >= d) ? s[tid - d] : 0;
        __syncthreads();
        s[tid] += t;
        __syncthreads();
    }
    int excl = s[tid] - v;
    bbase[tid] = excl;
    gCur1[tid] = excl;
    if (tid == NBUCK - 1) bbase[NBUCK] = s[tid];
    for (int i = tid; i < ZN; i += NBUCK) sums[i] = 0.0f;
}

// ---- phase 1: LDS-binned scatter into bucket-contiguous binned[] -----------
__global__ __launch_bounds__(256) void k_binscat(
    const void* ei, int E, const int* flag,
    int* __restrict__ gCur1, u32* __restrict__ binned) {
    __shared__ u32 stage[CHUNK];
    __shared__ int cnt[NBUCK], offsx[NBUCK], cur[NBUCK], gbase[NBUCK], scn[NBUCK];
    int tid = threadIdx.x;
    long base = (long)blockIdx.x * CHUNK;
    int is64 = *flag;
    if (tid < NBUCK) { cnt[tid] = 0; cur[tid] = 0; }
    __syncthreads();
    u32 rec[KPT];
#pragma unroll
    for (int k = 0; k < KPT; ++k) {
        long e = base + k * 256 + tid;
        u32 r = 0xFFFFFFFFu;
        if (e < E) {
            int s = idx_at(ei, e, is64);
            int d = idx_at(ei, (long)E + e, is64);
            r = ((u32)d << 16) | (u32)s;
            atomicAdd(&cnt[d >> 9], 1);
        }
        rec[k] = r;
    }
    __syncthreads();
    if (tid < NBUCK) scn[tid] = cnt[tid];
    __syncthreads();
    for (int d = 1; d < NBUCK; d <<= 1) {
        int t2 = 0;
        if (tid < NBUCK && tid >= d) t2 = scn[tid - d];
        __syncthreads();
        if (tid < NBUCK) scn[tid] += t2;
        __syncthreads();
    }
    if (tid < NBUCK) offsx[tid] = scn[tid] - cnt[tid];
    __syncthreads();
#pragma unroll
    for (int k = 0; k < KPT; ++k) {
        u32 r = rec[k];
        if (r != 0xFFFFFFFFu) {
            int bk = r >> 25;
            int p = offsx[bk] + atomicAdd(&cur[bk], 1);
            stage[p] = r;
        }
    }
    __syncthreads();
    if (tid < NBUCK && cnt[tid] > 0)
        gbase[tid] = atomicAdd(&gCur1[tid], cnt[tid]);
    __syncthreads();
    int total = scn[NBUCK - 1];
    for (int i = tid; i < total; i += 256) {
        u32 r = stage[i];
        int bk = r >> 25;
        binned[gbase[bk] + (i - offsx[bk])] = r;
    }
}

// ---- phase 2 (fused): per-node counts, padded offsets, dinv, csr fill ------
__global__ __launch_bounds__(512) void k_csrfill(
    const u32* __restrict__ binned, const int* __restrict__ bbase,
    int* __restrict__ offs, int* __restrict__ degi, float* __restrict__ dinv,
    u16* __restrict__ csr, int N) {
    __shared__ int lcnt[512];
    __shared__ int lcur[512];
    int b = blockIdx.x;
    int n0 = b << 9;
    int nn = N - n0; if (nn > 512) nn = 512;
    int tid = threadIdx.x;
    lcnt[tid] = 0;
    __syncthreads();
    int rbeg = bbase[b], rend = bbase[b + 1];
    for (int i = rbeg + tid; i < rend; i += 512)
        atomicAdd(&lcnt[(int)(binned[i] >> 16) - n0], 1);
    __syncthreads();
    int v = lcnt[tid];              // raw degree
    int pv = (v + 7) & ~7;          // padded
    __syncthreads();
    lcnt[tid] = pv;
    __syncthreads();
    for (int d = 1; d < 512; d <<= 1) {
        int t2 = (tid >= d) ? lcnt[tid - d] : 0;
        __syncthreads();
        lcnt[tid] += t2;
        __syncthreads();
    }
    int pexcl = lcnt[tid] - pv;
    int pbase = bbase[b] + (b << 12);    // raw base + worst-case pad slack
    int o = pbase + pexcl;
    if (tid < nn) {
        offs[n0 + tid] = o;
        degi[n0 + tid] = v;
        dinv[n0 + tid] = rsqrtf((float)v + 1.0f);
        lcur[tid] = o;
    }
    __syncthreads();
    for (int i = rbeg + tid; i < rend; i += 512) {
        u32 r = binned[i];
        int pos = atomicAdd(&lcur[(int)(r >> 16) - n0], 1);
        csr[pos] = (u16)(r & 0xFFFFu);
    }
}

// ---- converts --------------------------------------------------------------
__global__ void k_cvt_w(const float* __restrict__ W0, const float* __restrict__ W1,
                        const float* __restrict__ W2, u16* __restrict__ wsw) {
    int t = blockIdx.x * 256 + threadIdx.x;
    if (t >= 3 * 4096) return;
    int layer = t >> 12, r = t & 4095;
    int nt = r >> 10, ks = (r >> 9) & 1, lane = (r >> 3) & 63, j = r & 7;
    const float* W = (layer == 0) ? W0 : ((layer == 1) ? W1 : W2);
    int k = ks * 32 + (lane >> 4) * 8 + j;
    int n = nt * 16 + (lane & 15);
    wsw[t] = f2bf(W[k * 64 + n]);
}

// ---- MFMA GEMM: Hout[row] = bf16( dinv[row] * (A[row] @ W) ) ---------------
__global__ __launch_bounds__(256) void k_gemm_mfma(
    const u16* __restrict__ Ab, const float* __restrict__ Af,
    const u16* __restrict__ Wsw, const float* __restrict__ dinv,
    u16* __restrict__ Hout, int N, int use_f32) {
    int wid = blockIdx.x * 4 + (threadIdx.x >> 6);
    int lane = threadIdx.x & 63;
    int row0 = wid * 16;
    if (row0 >= N) return;
    int rl = lane & 15, kg = lane >> 4;
    int arow = row0 + rl; if (arow >= N) arow = N - 1;
    bfrag a0, a1;
    if (use_f32) {
        const float* r = Af + (long)arow * 64 + kg * 8;
        float4 v0 = *(const float4*)(r);
        float4 v1 = *(const float4*)(r + 4);
        float4 v2 = *(const float4*)(r + 32);
        float4 v3 = *(const float4*)(r + 36);
        a0[0] = (short)f2bf(v0.x); a0[1] = (short)f2bf(v0.y);
        a0[2] = (short)f2bf(v0.z); a0[3] = (short)f2bf(v0.w);
        a0[4] = (short)f2bf(v1.x); a0[5] = (short)f2bf(v1.y);
        a0[6] = (short)f2bf(v1.z); a0[7] = (short)f2bf(v1.w);
        a1[0] = (short)f2bf(v2.x); a1[1] = (short)f2bf(v2.y);
        a1[2] = (short)f2bf(v2.z); a1[3] = (short)f2bf(v2.w);
        a1[4] = (short)f2bf(v3.x); a1[5] = (short)f2bf(v3.y);
        a1[6] = (short)f2bf(v3.z); a1[7] = (short)f2bf(v3.w);
    } else {
        a0 = *(const bfrag*)(Ab + (long)arow * 64 + kg * 8);
        a1 = *(const bfrag*)(Ab + (long)arow * 64 + 32 + kg * 8);
    }
    float d4[4];
#pragma unroll
    for (int i = 0; i < 4; ++i) {
        int row = row0 + kg * 4 + i;
        d4[i] = (row < N) ? dinv[row] : 0.0f;
    }
#pragma unroll
    for (int nt = 0; nt < 4; ++nt) {
        bfrag b0 = *(const bfrag*)(Wsw + ((nt * 2 + 0) * 64 + lane) * 8);
        bfrag b1 = *(const bfrag*)(Wsw + ((nt * 2 + 1) * 64 + lane) * 8);
        f32x4 acc = {0.0f, 0.0f, 0.0f, 0.0f};
        acc = __builtin_amdgcn_mfma_f32_16x16x32_bf16(a0, b0, acc, 0, 0, 0);
        acc = __builtin_amdgcn_mfma_f32_16x16x32_bf16(a1, b1, acc, 0, 0, 0);
        int col = nt * 16 + rl;
#pragma unroll
        for (int i = 0; i < 4; ++i) {
            int row = row0 + kg * 4 + i;
            if (row < N) Hout[(long)row * 64 + col] = f2bf(d4[i] * acc[i]);
        }
    }
}

// ---- per-node aggregate: 16-lane teams, aligned ushort4 id loads, 8-deep ---
// all layers write bf16 Gb (layer 2 feeds bf16 pooling)
__global__ __launch_bounds__(256) void k_agg(
    const u16* __restrict__ csr, const int* __restrict__ offs,
    const int* __restrict__ degi, const float* __restrict__ dinv,
    const u16* __restrict__ Hb, const float* __restrict__ b,
    u16* __restrict__ Gb, int N, int mode, u32 k0, u32 k1) {
    int node = (int)(((long)blockIdx.x * blockDim.x + threadIdx.x) >> 6);
    int lane = threadIdx.x & 63;
    if (node >= N) return;
    int t = lane >> 4;        // team 0..3 (8-edge slice per 32-block)
    int q = lane & 15;        // feature quad: feats 4q..4q+3
    int beg = offs[node];     // 8-aligned
    int deg = degi[node];
    float a0 = 0.0f, a1 = 0.0f, a2 = 0.0f, a3 = 0.0f;
    int toff = t << 3;
    for (int g = 0; g < deg; g += 32) {
        int rem = deg - g;
        if (toff < rem) {
            const u16* cp = csr + beg + g + toff;
            ushort4 cA = *(const ushort4*)cp;        // aligned: beg%8==0
            ushort4 cB = *(const ushort4*)(cp + 4);
            u16 ids[8] = {cA.x, cA.y, cA.z, cA.w, cB.x, cB.y, cB.z, cB.w};
            int tcnt = rem - toff;                   // valid for this team
#pragma unroll
            for (int u = 0; u < 8; ++u) {
                uint2 d = *(const uint2*)(Hb + ((long)ids[u] << 6) + (q << 2));
                u32 dx = (u < tcnt) ? d.x : 0u;
                u32 dy = (u < tcnt) ? d.y : 0u;
                a0 += __uint_as_float(dx << 16);
                a1 += __uint_as_float(dx & 0xffff0000u);
                a2 += __uint_as_float(dy << 16);
                a3 += __uint_as_float(dy & 0xffff0000u);
            }
        }
    }
    a0 += __shfl_xor(a0, 16); a1 += __shfl_xor(a1, 16);
    a2 += __shfl_xor(a2, 16); a3 += __shfl_xor(a3, 16);
    a0 += __shfl_xor(a0, 32); a1 += __shfl_xor(a1, 32);
    a2 += __shfl_xor(a2, 32); a3 += __shfl_xor(a3, 32);
    int f = (q << 2) + t;
    float av = (t == 0) ? a0 : (t == 1) ? a1 : (t == 2) ? a2 : a3;
    float di = dinv[node];
    float hn = bf2f(Hb[((long)node << 6) + f]);
    float v = di * (av + hn) + b[f];
    long idx = ((long)node << 6) + f;
    if (mode) {
        v = fmaxf(v, 0.0f);
        v = drop_scale(v, k0, k1, (u32)idx);
    }
    Gb[idx] = f2bf(v);
}

// ---- pooling: bf16 input, run-length atomics -------------------------------
__global__ void k_poolsum(const u16* __restrict__ Gb, const void* batch,
                          const int* flag, int N,
                          float* __restrict__ sums, float* __restrict__ cnt) {
    int wave = (int)(((long)blockIdx.x * blockDim.x + threadIdx.x) >> 6);
    int f = threadIdx.x & 63;
    int n0 = wave * 8;
    if (n0 >= N) return;
    int nend = n0 + 8 < N ? n0 + 8 : N;
    int is64 = *flag;
    float acc = 0.0f; float cacc = 0.0f; int curg = -1;
    for (int n = n0; n < nend; ++n) {
        int g = idx_at(batch, n, is64);
        if (g != curg) {
            if (curg >= 0) {
                atomicAdd(&sums[curg * 64 + f], acc);
                if (f == 0) atomicAdd(&cnt[curg], cacc);
            }
            curg = g; acc = 0.0f; cacc = 0.0f;
        }
        acc += bf2f(Gb[(long)n * 64 + f]);
        cacc += 1.0f;
    }
    if (curg >= 0) {
        atomicAdd(&sums[curg * 64 + f], acc);
        if (f == 0) atomicAdd(&cnt[curg], cacc);
    }
}

// ---- fused pool-finalize + output GEMM: 1 block per graph ------------------
__global__ void k_poolout(const float* __restrict__ sums, const float* __restrict__ cnt,
                          const float* __restrict__ Wl, const float* __restrict__ bl,
                          float* __restrict__ out, u32 k0, u32 k1, int O) {
    __shared__ float p_sh[64];
    int g = blockIdx.x;
    int t = threadIdx.x;           // 64 threads
    float c = fmaxf(cnt[g], 1.0f);
    float pv = drop_scale(sums[g * 64 + t] / c, k0, k1, (u32)(g * 64 + t));
    p_sh[t] = pv;
    __syncthreads();
    if (t < O) {
        float acc = bl[t];
#pragma unroll 8
        for (int k = 0; k < 64; ++k) acc += p_sh[k] * Wl[k * O + t];
        out[g * O + t] = acc;
    }
}

// ---- launch ----------------------------------------------------------------
extern "C" void kernel_launch(void* const* d_in, const int* in_sizes, int n_in,
                              void* d_out, int out_size, void* d_ws, size_t ws_size,
                              hipStream_t stream) {
    const float* x  = (const float*)d_in[0];
    const void*  ei = d_in[1];
    const void*  bt = d_in[2];
    const float* W[3] = {(const float*)d_in[3], (const float*)d_in[5], (const float*)d_in[7]};
    const float* b[3] = {(const float*)d_in[4], (const float*)d_in[6], (const float*)d_in[8]};
    const float* Wl = (const float*)d_in[9];
    const float* bl = (const float*)d_in[10];
    float* out = (float*)d_out;

    const int F = 64;
    int N  = in_sizes[0] / F;      // 50000  (< 65536: u16 node ids)
    int E  = in_sizes[1] / 2;      // 800000
    int NG = 256;
    int O  = in_sizes[9] / F;      // 10
    long NF = (long)N * F;         // 3.2M
    int Np = ((N + 63) / 64) * 64;
    int NB = (N + 511) >> 9;       // coarse buckets (98)

    auto align256 = [](char*& p) { p = (char*)(((size_t)p + 255) & ~(size_t)255); };
    char* wp = (char*)d_ws;
    align256(wp); float* dinv   = (float*)wp;  wp += (size_t)Np * 4;
    align256(wp); int*   degi   = (int*)wp;    wp += (size_t)Np * 4;
    align256(wp); int*   offs   = (int*)wp;    wp += (size_t)(Np + 64) * 4;
    align256(wp); int*   flag   = (int*)wp;    wp += 256;
    align256(wp); int*   gCnt   = (int*)wp;    wp += NBUCK * 4;
    align256(wp); int*   bbase  = (int*)wp;    wp += (NBUCK + 64) * 4;
    align256(wp); int*   gCur1  = (int*)wp;    wp += NBUCK * 4;
    align256(wp); float* sums   = (float*)wp;  wp += (size_t)NG * F * 4;
    align256(wp); float* cnt    = (float*)wp;  wp += (size_t)NG * 4;
    align256(wp); u16*   wsw    = (u16*)wp;    wp += 3 * 4096 * 2;
    align256(wp); u32*   binned = (u32*)wp;    wp += (size_t)E * 4;
    align256(wp); u16*   csr    = (u16*)wp;    wp += ((size_t)E + (size_t)NBUCK * 4096 + 64) * 2;
    align256(wp); u16*   Hb     = (u16*)wp;    wp += NF * 2;
    align256(wp); u16*   Gb     = (u16*)wp;    wp += NF * 2;

    u32 dk[3][2];
    for (u32 i = 0; i < 3; ++i) tf2x32(0u, 12345u, 0u, i, &dk[i][0], &dk[i][1]);

    int EB = (E + CHUNK - 1) / CHUNK;   // edge-chunk blocks
    int ZN = NG * F + NG;               // floats to zero (sums+cnt contiguous)

    k_detect<<<1, 128, 0, stream>>>((const u32*)ei, flag, gCnt);
    k_bcnt<<<EB, 256, 0, stream>>>(ei, E, flag, gCnt);
    k_bscan<<<1, NBUCK, 0, stream>>>(gCnt, bbase, gCur1, sums, ZN);
    k_binscat<<<EB, 256, 0, stream>>>(ei, E, flag, gCur1, binned);
    k_csrfill<<<NB, 512, 0, stream>>>(binned, bbase, offs, degi, dinv, csr, N);

    k_cvt_w<<<48, 256, 0, stream>>>(W[0], W[1], W[2], wsw);

    int gemmBlocks = ((N + 15) / 16 + 3) / 4;
    int aggBlocks = (int)(((long)N * 64 + 255) / 256);
    for (int l = 0; l < 3; ++l) {
        k_gemm_mfma<<<gemmBlocks, 256, 0, stream>>>(Gb, x, wsw + l * 4096, dinv,
                                                    Hb, N, (l == 0) ? 1 : 0);
        k_agg<<<aggBlocks, 256, 0, stream>>>(csr, offs, degi, dinv, Hb, b[l],
                                             Gb, N, (l < 2) ? 1 : 0,
                                             dk[l][0], dk[l][1]);
    }

    int pw = (N + 7) / 8;  // pooling waves
    k_poolsum<<<(int)(((long)pw * 64 + 255) / 256), 256, 0, stream>>>(Gb, bt, flag, N, sums, cnt);
    k_poolout<<<NG, 64, 0, stream>>>(sums, cnt, Wl, bl, out, dk[2][0], dk[2][1], O);
}

// Round 9
// 141.042 us; speedup vs baseline: 6.5353x; 1.2414x over previous
//
#include <hip/hip_runtime.h>

typedef unsigned int u32;
typedef unsigned short u16;
using bfrag  = __attribute__((ext_vector_type(8))) short;   // 8 bf16
using f32x4  = __attribute__((ext_vector_type(4))) float;   // MFMA acc

#define CHUNK 4096
#define KPT 16
#define NBUCK 128
#define BCAP 10496                    // per-bucket binned capacity (mean 8163 + 26 sigma)
#define CSRCAP (BCAP + 4096)          // + worst-case padding (512 nodes * 7)

// ---- JAX threefry2x32 (20 rounds), bit-exact -------------------------------
__host__ __device__ inline void tf2x32(u32 k0, u32 k1, u32 x0, u32 x1,
                                       u32* y0, u32* y1) {
    u32 ks2 = k0 ^ k1 ^ 0x1BD11BDAu;
#define TFR(r) { x0 += x1; x1 = (x1 << (r)) | (x1 >> (32 - (r))); x1 ^= x0; }
    x0 += k0; x1 += k1;
    TFR(13) TFR(15) TFR(26) TFR(6)
    x0 += k1;  x1 += ks2 + 1u;
    TFR(17) TFR(29) TFR(16) TFR(24)
    x0 += ks2; x1 += k0 + 2u;
    TFR(13) TFR(15) TFR(26) TFR(6)
    x0 += k0;  x1 += k1 + 3u;
    TFR(17) TFR(29) TFR(16) TFR(24)
    x0 += k1;  x1 += ks2 + 4u;
    TFR(13) TFR(15) TFR(26) TFR(6)
    x0 += ks2; x1 += k0 + 5u;
#undef TFR
    *y0 = x0; *y1 = x1;
}

__device__ inline float drop_scale(float v, u32 k0, u32 k1, u32 idx) {
    u32 y0, y1;
    tf2x32(k0, k1, 0u, idx, &y0, &y1);
    u32 bits = y0 ^ y1;
    float u = __uint_as_float((bits >> 9) | 0x3f800000u) - 1.0f;
    return (u < 0.7f) ? (v / 0.7f) : 0.0f;
}

// bf16 helpers
__device__ inline u16 f2bf(float f) {
    u32 u = __float_as_uint(f);
    u32 r = (u + 0x7fffu + ((u >> 16) & 1u)) >> 16;
    return (u16)r;
}
__device__ inline float bf2f(u16 h) { return __uint_as_float(((u32)h) << 16); }

__device__ inline int idx_at(const void* p, long i, int is64) {
    return is64 ? (int)((const long long*)p)[i] : ((const int*)p)[i];
}

// ---- init: detect idx dtype, init bucket cursors, convert W ----------------
// block 0: housekeeping; blocks 1..48: W[64][64]x3 -> bf16 MFMA B-frag order
__global__ void k_init(const u32* p, int* flag, int* gCur1,
                       const float* __restrict__ W0, const float* __restrict__ W1,
                       const float* __restrict__ W2, u16* __restrict__ wsw) {
    if (blockIdx.x == 0) {
        int tid = threadIdx.x;
        if (tid < NBUCK) gCur1[tid] = tid * BCAP;
        if (tid == 0) {
            int all0 = 1;
            for (int i = 0; i < 64; ++i)
                if (p[2 * i + 1] != 0u) { all0 = 0; break; }
            *flag = all0;   // 1 => int64 layout
        }
        return;
    }
    int t = (blockIdx.x - 1) * 256 + threadIdx.x;
    if (t >= 3 * 4096) return;
    int layer = t >> 12, r = t & 4095;
    int nt = r >> 10, ks = (r >> 9) & 1, lane = (r >> 3) & 63, j = r & 7;
    const float* W = (layer == 0) ? W0 : ((layer == 1) ? W1 : W2);
    int k = ks * 32 + (lane >> 4) * 8 + j;
    int n = nt * 16 + (lane & 15);
    wsw[t] = f2bf(W[k * 64 + n]);
}

// ---- phase 1: LDS-binned scatter into fixed-capacity bucket regions --------
__global__ __launch_bounds__(256) void k_binscat(
    const void* ei, int E, const int* flag,
    int* __restrict__ gCur1, u32* __restrict__ binned) {
    __shared__ u32 stage[CHUNK];
    __shared__ int cnt[NBUCK], offsx[NBUCK], cur[NBUCK], gbase[NBUCK], scn[NBUCK];
    int tid = threadIdx.x;
    long base = (long)blockIdx.x * CHUNK;
    int is64 = *flag;
    if (tid < NBUCK) { cnt[tid] = 0; cur[tid] = 0; }
    __syncthreads();
    u32 rec[KPT];
#pragma unroll
    for (int k = 0; k < KPT; ++k) {
        long e = base + k * 256 + tid;
        u32 r = 0xFFFFFFFFu;
        if (e < E) {
            int s = idx_at(ei, e, is64);
            int d = idx_at(ei, (long)E + e, is64);
            r = ((u32)d << 16) | (u32)s;
            atomicAdd(&cnt[d >> 9], 1);
        }
        rec[k] = r;
    }
    __syncthreads();
    if (tid < NBUCK) scn[tid] = cnt[tid];
    __syncthreads();
    for (int d = 1; d < NBUCK; d <<= 1) {
        int t2 = 0;
        if (tid < NBUCK && tid >= d) t2 = scn[tid - d];
        __syncthreads();
        if (tid < NBUCK) scn[tid] += t2;
        __syncthreads();
    }
    if (tid < NBUCK) offsx[tid] = scn[tid] - cnt[tid];
    __syncthreads();
#pragma unroll
    for (int k = 0; k < KPT; ++k) {
        u32 r = rec[k];
        if (r != 0xFFFFFFFFu) {
            int bk = r >> 25;
            int p = offsx[bk] + atomicAdd(&cur[bk], 1);
            stage[p] = r;
        }
    }
    __syncthreads();
    if (tid < NBUCK && cnt[tid] > 0)
        gbase[tid] = atomicAdd(&gCur1[tid], cnt[tid]);
    __syncthreads();
    int total = scn[NBUCK - 1];
    for (int i = tid; i < total; i += 256) {
        u32 r = stage[i];
        int bk = r >> 25;
        binned[gbase[bk] + (i - offsx[bk])] = r;
    }
}

// ---- phase 2 (fused): per-node counts, padded offsets, dinv, csr fill ------
__global__ __launch_bounds__(512) void k_csrfill(
    const u32* __restrict__ binned, const int* __restrict__ gCur1,
    int* __restrict__ offs, int* __restrict__ degi, float* __restrict__ dinv,
    u16* __restrict__ csr, int N) {
    __shared__ int lcnt[512];
    __shared__ int lcur[512];
    int b = blockIdx.x;
    int n0 = b << 9;
    int nn = N - n0; if (nn > 512) nn = 512;
    int tid = threadIdx.x;
    lcnt[tid] = 0;
    __syncthreads();
    int rbeg = b * BCAP, rend = gCur1[b];
    for (int i = rbeg + tid; i < rend; i += 512)
        atomicAdd(&lcnt[(int)(binned[i] >> 16) - n0], 1);
    __syncthreads();
    int v = lcnt[tid];              // raw degree
    int pv = (v + 7) & ~7;          // padded to 8
    __syncthreads();
    lcnt[tid] = pv;
    __syncthreads();
    for (int d = 1; d < 512; d <<= 1) {
        int t2 = (tid >= d) ? lcnt[tid - d] : 0;
        __syncthreads();
        lcnt[tid] += t2;
        __syncthreads();
    }
    int pexcl = lcnt[tid] - pv;
    int o = b * CSRCAP + pexcl;
    if (tid < nn) {
        offs[n0 + tid] = o;
        degi[n0 + tid] = v;
        dinv[n0 + tid] = rsqrtf((float)v + 1.0f);
        lcur[tid] = o;
    }
    __syncthreads();
    for (int i = rbeg + tid; i < rend; i += 512) {
        u32 r = binned[i];
        int pos = atomicAdd(&lcur[(int)(r >> 16) - n0], 1);
        csr[pos] = (u16)(r & 0xFFFFu);
    }
}

// ---- MFMA GEMM: Hout[row] = bf16( dinv[row] * (A[row] @ W) ) ---------------
__global__ __launch_bounds__(256) void k_gemm_mfma(
    const u16* __restrict__ Ab, const float* __restrict__ Af,
    const u16* __restrict__ Wsw, const float* __restrict__ dinv,
    u16* __restrict__ Hout, int N, int use_f32) {
    int wid = blockIdx.x * 4 + (threadIdx.x >> 6);
    int lane = threadIdx.x & 63;
    int row0 = wid * 16;
    if (row0 >= N) return;
    int rl = lane & 15, kg = lane >> 4;
    int arow = row0 + rl; if (arow >= N) arow = N - 1;
    bfrag a0, a1;
    if (use_f32) {
        const float* r = Af + (long)arow * 64 + kg * 8;
        float4 v0 = *(const float4*)(r);
        float4 v1 = *(const float4*)(r + 4);
        float4 v2 = *(const float4*)(r + 32);
        float4 v3 = *(const float4*)(r + 36);
        a0[0] = (short)f2bf(v0.x); a0[1] = (short)f2bf(v0.y);
        a0[2] = (short)f2bf(v0.z); a0[3] = (short)f2bf(v0.w);
        a0[4] = (short)f2bf(v1.x); a0[5] = (short)f2bf(v1.y);
        a0[6] = (short)f2bf(v1.z); a0[7] = (short)f2bf(v1.w);
        a1[0] = (short)f2bf(v2.x); a1[1] = (short)f2bf(v2.y);
        a1[2] = (short)f2bf(v2.z); a1[3] = (short)f2bf(v2.w);
        a1[4] = (short)f2bf(v3.x); a1[5] = (short)f2bf(v3.y);
        a1[6] = (short)f2bf(v3.z); a1[7] = (short)f2bf(v3.w);
    } else {
        a0 = *(const bfrag*)(Ab + (long)arow * 64 + kg * 8);
        a1 = *(const bfrag*)(Ab + (long)arow * 64 + 32 + kg * 8);
    }
    float d4[4];
#pragma unroll
    for (int i = 0; i < 4; ++i) {
        int row = row0 + kg * 4 + i;
        d4[i] = (row < N) ? dinv[row] : 0.0f;
    }
#pragma unroll
    for (int nt = 0; nt < 4; ++nt) {
        bfrag b0 = *(const bfrag*)(Wsw + ((nt * 2 + 0) * 64 + lane) * 8);
        bfrag b1 = *(const bfrag*)(Wsw + ((nt * 2 + 1) * 64 + lane) * 8);
        f32x4 acc = {0.0f, 0.0f, 0.0f, 0.0f};
        acc = __builtin_amdgcn_mfma_f32_16x16x32_bf16(a0, b0, acc, 0, 0, 0);
        acc = __builtin_amdgcn_mfma_f32_16x16x32_bf16(a1, b1, acc, 0, 0, 0);
        int col = nt * 16 + rl;
#pragma unroll
        for (int i = 0; i < 4; ++i) {
            int row = row0 + kg * 4 + i;
            if (row < N) Hout[(long)row * 64 + col] = f2bf(d4[i] * acc[i]);
        }
    }
}

// ---- per-node aggregate: 16-lane TEAM PER NODE, 4 nodes/wave ---------------
// lane q of team handles feats 4q..4q+3; packed ushort4 output write.
__global__ __launch_bounds__(256) void k_agg(
    const u16* __restrict__ csr, const int* __restrict__ offs,
    const int* __restrict__ degi, const float* __restrict__ dinv,
    const u16* __restrict__ Hb, const float* __restrict__ b,
    u16* __restrict__ Gb, int N, int mode, u32 k0, u32 k1) {
    long t = (long)blockIdx.x * blockDim.x + threadIdx.x;
    int node = (int)(t >> 4);
    int q = (int)(t & 15);
    if (node >= N) return;
    int beg = offs[node];     // 8-aligned
    int deg = degi[node];
    float a0 = 0.0f, a1 = 0.0f, a2 = 0.0f, a3 = 0.0f;
    for (int g = 0; g < deg; g += 8) {
        const u16* cp = csr + beg + g;           // 16B-aligned, team-uniform
        ushort4 cA = *(const ushort4*)cp;
        ushort4 cB = *(const ushort4*)(cp + 4);
        u16 ids[8] = {cA.x, cA.y, cA.z, cA.w, cB.x, cB.y, cB.z, cB.w};
        int rem = deg - g;
#pragma unroll
        for (int u = 0; u < 8; ++u) {
            uint2 d = *(const uint2*)(Hb + ((long)ids[u] << 6) + (q << 2));
            u32 dx = (u < rem) ? d.x : 0u;
            u32 dy = (u < rem) ? d.y : 0u;
            a0 += __uint_as_float(dx << 16);
            a1 += __uint_as_float(dx & 0xffff0000u);
            a2 += __uint_as_float(dy << 16);
            a3 += __uint_as_float(dy & 0xffff0000u);
        }
    }
    float di = dinv[node];
    uint2 hd = *(const uint2*)(Hb + ((long)node << 6) + (q << 2));
    float4 bv = *(const float4*)(b + (q << 2));
    float v0 = di * (a0 + __uint_as_float(hd.x << 16))        + bv.x;
    float v1 = di * (a1 + __uint_as_float(hd.x & 0xffff0000u)) + bv.y;
    float v2 = di * (a2 + __uint_as_float(hd.y << 16))        + bv.z;
    float v3 = di * (a3 + __uint_as_float(hd.y & 0xffff0000u)) + bv.w;
    u32 idx = ((u32)node << 6) + (q << 2);
    if (mode) {
        v0 = drop_scale(fmaxf(v0, 0.0f), k0, k1, idx + 0);
        v1 = drop_scale(fmaxf(v1, 0.0f), k0, k1, idx + 1);
        v2 = drop_scale(fmaxf(v2, 0.0f), k0, k1, idx + 2);
        v3 = drop_scale(fmaxf(v3, 0.0f), k0, k1, idx + 3);
    }
    ushort4 o; o.x = f2bf(v0); o.y = f2bf(v1); o.z = f2bf(v2); o.w = f2bf(v3);
    *(ushort4*)(Gb + idx) = o;
}

// ---- pooling: bf16 input, run-length atomics; zero sums first --------------
__global__ void k_zero(float* __restrict__ sums, int ZN) {
    int i = blockIdx.x * 256 + threadIdx.x;
    if (i < ZN) sums[i] = 0.0f;
}

__global__ void k_poolsum(const u16* __restrict__ Gb, const void* batch,
                          const int* flag, int N,
                          float* __restrict__ sums, float* __restrict__ cnt) {
    int wave = (int)(((long)blockIdx.x * blockDim.x + threadIdx.x) >> 6);
    int f = threadIdx.x & 63;
    int n0 = wave * 8;
    if (n0 >= N) return;
    int nend = n0 + 8 < N ? n0 + 8 : N;
    int is64 = *flag;
    float acc = 0.0f; float cacc = 0.0f; int curg = -1;
    for (int n = n0; n < nend; ++n) {
        int g = idx_at(batch, n, is64);
        if (g != curg) {
            if (curg >= 0) {
                atomicAdd(&sums[curg * 64 + f], acc);
                if (f == 0) atomicAdd(&cnt[curg], cacc);
            }
            curg = g; acc = 0.0f; cacc = 0.0f;
        }
        acc += bf2f(Gb[(long)n * 64 + f]);
        cacc += 1.0f;
    }
    if (curg >= 0) {
        atomicAdd(&sums[curg * 64 + f], acc);
        if (f == 0) atomicAdd(&cnt[curg], cacc);
    }
}

// ---- fused pool-finalize + output GEMM: 1 block per graph ------------------
__global__ void k_poolout(const float* __restrict__ sums, const float* __restrict__ cnt,
                          const float* __restrict__ Wl, const float* __restrict__ bl,
                          float* __restrict__ out, u32 k0, u32 k1, int O) {
    __shared__ float p_sh[64];
    int g = blockIdx.x;
    int t = threadIdx.x;           // 64 threads
    float c = fmaxf(cnt[g], 1.0f);
    float pv = drop_scale(sums[g * 64 + t] / c, k0, k1, (u32)(g * 64 + t));
    p_sh[t] = pv;
    __syncthreads();
    if (t < O) {
        float acc = bl[t];
#pragma unroll 8
        for (int k = 0; k < 64; ++k) acc += p_sh[k] * Wl[k * O + t];
        out[g * O + t] = acc;
    }
}

// ---- launch ----------------------------------------------------------------
extern "C" void kernel_launch(void* const* d_in, const int* in_sizes, int n_in,
                              void* d_out, int out_size, void* d_ws, size_t ws_size,
                              hipStream_t stream) {
    const float* x  = (const float*)d_in[0];
    const void*  ei = d_in[1];
    const void*  bt = d_in[2];
    const float* W[3] = {(const float*)d_in[3], (const float*)d_in[5], (const float*)d_in[7]};
    const float* b[3] = {(const float*)d_in[4], (const float*)d_in[6], (const float*)d_in[8]};
    const float* Wl = (const float*)d_in[9];
    const float* bl = (const float*)d_in[10];
    float* out = (float*)d_out;

    const int F = 64;
    int N  = in_sizes[0] / F;      // 50000  (< 65536: u16 node ids)
    int E  = in_sizes[1] / 2;      // 800000
    int NG = 256;
    int O  = in_sizes[9] / F;      // 10
    long NF = (long)N * F;         // 3.2M
    int Np = ((N + 63) / 64) * 64;
    int NB = (N + 511) >> 9;       // coarse buckets (98)

    auto align256 = [](char*& p) { p = (char*)(((size_t)p + 255) & ~(size_t)255); };
    char* wp = (char*)d_ws;
    align256(wp); float* dinv   = (float*)wp;  wp += (size_t)Np * 4;
    align256(wp); int*   degi   = (int*)wp;    wp += (size_t)Np * 4;
    align256(wp); int*   offs   = (int*)wp;    wp += (size_t)Np * 4;
    align256(wp); int*   flag   = (int*)wp;    wp += 256;
    align256(wp); int*   gCur1  = (int*)wp;    wp += NBUCK * 4;
    align256(wp); float* sums   = (float*)wp;  wp += (size_t)NG * F * 4;
    align256(wp); float* cnt    = (float*)wp;  wp += (size_t)NG * 4;
    align256(wp); u16*   wsw    = (u16*)wp;    wp += 3 * 4096 * 2;
    align256(wp); u32*   binned = (u32*)wp;    wp += (size_t)NBUCK * BCAP * 4;
    align256(wp); u16*   csr    = (u16*)wp;    wp += (size_t)NBUCK * CSRCAP * 2;
    align256(wp); u16*   Hb     = (u16*)wp;    wp += NF * 2;
    align256(wp); u16*   Gb     = (u16*)wp;    wp += NF * 2;

    u32 dk[3][2];
    for (u32 i = 0; i < 3; ++i) tf2x32(0u, 12345u, 0u, i, &dk[i][0], &dk[i][1]);

    int EB = (E + CHUNK - 1) / CHUNK;   // edge-chunk blocks
    int ZN = NG * F + NG;               // floats to zero (sums+cnt contiguous)

    k_init<<<49, 256, 0, stream>>>((const u32*)ei, flag, gCur1,
                                   W[0], W[1], W[2], wsw);
    k_binscat<<<EB, 256, 0, stream>>>(ei, E, flag, gCur1, binned);
    k_csrfill<<<NB, 512, 0, stream>>>(binned, gCur1, offs, degi, dinv, csr, N);
    k_zero<<<(ZN + 255) / 256, 256, 0, stream>>>(sums, ZN);

    int gemmBlocks = ((N + 15) / 16 + 3) / 4;
    int aggBlocks = (int)(((long)N * 16 + 255) / 256);
    for (int l = 0; l < 3; ++l) {
        k_gemm_mfma<<<gemmBlocks, 256, 0, stream>>>(Gb, x, wsw + l * 4096, dinv,
                                                    Hb, N, (l == 0) ? 1 : 0);
        k_agg<<<aggBlocks, 256, 0, stream>>>(csr, offs, degi, dinv, Hb, b[l],
                                             Gb, N, (l < 2) ? 1 : 0,
                                             dk[l][0], dk[l][1]);
    }

    int pw = (N + 7) / 8;  // pooling waves
    k_poolsum<<<(int)(((long)pw * 64 + 255) / 256), 256, 0, stream>>>(Gb, bt, flag, N, sums, cnt);
    k_poolout<<<NG, 64, 0, stream>>>(sums, cnt, Wl, bl, out, dk[2][0], dk[2][1], O);
}